// Round 1
// baseline (940.414 us; speedup 1.0000x reference)
//
#include <hip/hip_runtime.h>
#include <hip/hip_bf16.h>

#define N_NODES 50000
#define N_GROUPS 50

typedef unsigned short u16x8 __attribute__((ext_vector_type(8)));
typedef __bf16 bf16x8 __attribute__((ext_vector_type(8)));
typedef float f32x4 __attribute__((ext_vector_type(4)));

// ---------- conversion kernels ----------
__global__ void cvt_f32_bf16(const float* __restrict__ in, __hip_bfloat16* __restrict__ out, int n) {
  int i = blockIdx.x * blockDim.x + threadIdx.x;
  int base = i * 4;
  if (base + 3 < n) {
    float4 v = *(const float4*)(in + base);
    out[base + 0] = __float2bfloat16(v.x);
    out[base + 1] = __float2bfloat16(v.y);
    out[base + 2] = __float2bfloat16(v.z);
    out[base + 3] = __float2bfloat16(v.w);
  } else {
    for (int k = base; k < n; ++k) out[k] = __float2bfloat16(in[k]);
  }
}

// out[c][r] = in[r][c]  (store transposed, bf16)
__global__ void cvt_transpose(const float* __restrict__ in, __hip_bfloat16* __restrict__ out, int R, int C) {
  int i = blockIdx.x * blockDim.x + threadIdx.x;
  if (i < R * C) {
    int r = i / C, c = i % C;
    out[(size_t)c * R + r] = __float2bfloat16(in[i]);
  }
}

__global__ void zero_i32(int* __restrict__ p, int n) {
  int i = blockIdx.x * blockDim.x + threadIdx.x;
  if (i < n) p[i] = 0;
}

// ---------- CSR build ----------
__global__ void count_deg(const int* __restrict__ dst, int* __restrict__ cnt, int e, int n) {
  int i = blockIdx.x * blockDim.x + threadIdx.x;
  if (i < e + n) {
    int d = (i < e) ? dst[i] : (i - e);   // self loops appended
    atomicAdd(&cnt[d], 1);
  }
}

__global__ void scan_kernel(const int* __restrict__ cnt, int* __restrict__ offs,
                            int* __restrict__ cur, int n) {
  __shared__ int part[1024];
  int tid = threadIdx.x;
  int chunk = (n + 1023) >> 10;
  int b = tid * chunk;
  int epos = b + chunk; if (epos > n) epos = n;
  int s = 0;
  for (int i = b; i < epos; ++i) s += cnt[i];
  part[tid] = s;
  __syncthreads();
  for (int d = 1; d < 1024; d <<= 1) {
    int v = 0;
    if (tid >= d) v = part[tid - d];
    __syncthreads();
    part[tid] += v;
    __syncthreads();
  }
  int base = part[tid] - s;  // exclusive prefix
  for (int i = b; i < epos; ++i) { offs[i] = base; cur[i] = base; base += cnt[i]; }
  if (b < n && epos == n) offs[n] = base;
}

__global__ void scatter_edges(const int* __restrict__ src, const int* __restrict__ dst,
                              int* __restrict__ cur, int* __restrict__ csr, int e, int n) {
  int i = blockIdx.x * blockDim.x + threadIdx.x;
  if (i < e + n) {
    int s, d;
    if (i < e) { s = src[i]; d = dst[i]; } else { s = i - e; d = i - e; }
    int pos = atomicAdd(&cur[d], 1);
    csr[pos] = s;
  }
}

__global__ void compute_dinv(const int* __restrict__ cnt, float* __restrict__ dinv, int n) {
  int i = blockIdx.x * blockDim.x + threadIdx.x;
  if (i < n) {
    int c = cnt[i]; if (c < 1) c = 1;
    dinv[i] = 1.0f / sqrtf((float)c);
  }
}

// ---------- bf16 MFMA GEMM: C[M][Nc] = A[M][K] * Bt[Nc][K]^T ----------
__global__ __launch_bounds__(256) void gemm_bt(
    const __hip_bfloat16* __restrict__ A, const __hip_bfloat16* __restrict__ Bt,
    float* __restrict__ C, int M, int Nc, int K) {
  __shared__ __hip_bfloat16 Ash[128][40];
  __shared__ __hip_bfloat16 Bsh[128][40];
  const int tid = threadIdx.x;
  const int lane = tid & 63;
  const int w = tid >> 6;
  const int wr = (w >> 1) * 64, wc = (w & 1) * 64;
  const int row0 = blockIdx.x * 128, col0 = blockIdx.y * 128;
  const int sr = tid >> 2;
  const int sc = (tid & 3) * 8;

  f32x4 zero4 = {0.f, 0.f, 0.f, 0.f};
  f32x4 acc[4][4];
#pragma unroll
  for (int i = 0; i < 4; i++)
#pragma unroll
    for (int j = 0; j < 4; j++) acc[i][j] = zero4;

  u16x8 z8 = {0, 0, 0, 0, 0, 0, 0, 0};

  auto loadA = [&](int r, int k) -> u16x8 {
    int rr = row0 + r;
    if (rr < M) return *(const u16x8*)(A + (size_t)rr * K + k + sc);
    return z8;
  };
  auto loadB = [&](int r, int k) -> u16x8 {
    int rr = col0 + r;
    if (rr < Nc) return *(const u16x8*)(Bt + (size_t)rr * K + k + sc);
    return z8;
  };

  u16x8 ar0 = loadA(sr, 0), ar1 = loadA(sr + 64, 0);
  u16x8 br0 = loadB(sr, 0), br1 = loadB(sr + 64, 0);

  const int lrow = lane & 15;
  const int lk = (lane >> 4) * 8;

  for (int kt = 0; kt < K; kt += 32) {
    __syncthreads();
    *(u16x8*)&Ash[sr][sc] = ar0;
    *(u16x8*)&Ash[sr + 64][sc] = ar1;
    *(u16x8*)&Bsh[sr][sc] = br0;
    *(u16x8*)&Bsh[sr + 64][sc] = br1;
    __syncthreads();
    int kn = kt + 32;
    if (kn < K) {
      ar0 = loadA(sr, kn); ar1 = loadA(sr + 64, kn);
      br0 = loadB(sr, kn); br1 = loadB(sr + 64, kn);
    }
    bf16x8 av[4], bv[4];
#pragma unroll
    for (int i = 0; i < 4; i++) av[i] = *(const bf16x8*)&Ash[wr + i * 16 + lrow][lk];
#pragma unroll
    for (int j = 0; j < 4; j++) bv[j] = *(const bf16x8*)&Bsh[wc + j * 16 + lrow][lk];
#pragma unroll
    for (int i = 0; i < 4; i++)
#pragma unroll
      for (int j = 0; j < 4; j++)
        acc[i][j] = __builtin_amdgcn_mfma_f32_16x16x32_bf16(av[i], bv[j], acc[i][j], 0, 0, 0);
  }

#pragma unroll
  for (int i = 0; i < 4; i++) {
#pragma unroll
    for (int r = 0; r < 4; r++) {
      int rr = row0 + wr + i * 16 + (lane >> 4) * 4 + r;
      if (rr < M) {
#pragma unroll
        for (int j = 0; j < 4; j++) {
          int cc = col0 + wc + j * 16 + (lane & 15);
          if (cc < Nc) C[(size_t)rr * Nc + cc] = acc[i][j][r];
        }
      }
    }
  }
}

// ---------- per-node attention logits: a_src[n][h], a_dst[n][h] ----------
__global__ __launch_bounds__(256) void att_kernel(
    const float* __restrict__ h, const float* __restrict__ att_s, const float* __restrict__ att_d,
    float* __restrict__ a_src, float* __restrict__ a_dst, int n) {
  int wid = (int)(((size_t)blockIdx.x * blockDim.x + threadIdx.x) >> 6);
  if (wid >= n) return;
  int lane = threadIdx.x & 63;
  int c0 = lane * 4;
  float4 hv = *(const float4*)(h + (size_t)wid * 256 + c0);
  float4 as = *(const float4*)(att_s + c0);
  float4 ad = *(const float4*)(att_d + c0);
  float ds_ = hv.x * as.x + hv.y * as.y + hv.z * as.z + hv.w * as.w;
  float dd_ = hv.x * ad.x + hv.y * ad.y + hv.z * ad.z + hv.w * ad.w;
#pragma unroll
  for (int m = 1; m < 16; m <<= 1) {
    ds_ += __shfl_xor(ds_, m);
    dd_ += __shfl_xor(dd_, m);
  }
  if ((lane & 15) == 0) {
    a_src[wid * 4 + (lane >> 4)] = ds_;
    a_dst[wid * 4 + (lane >> 4)] = dd_;
  }
}

// ---------- GAT aggregate: one wave per dst node ----------
__global__ __launch_bounds__(256) void gat_aggregate(
    const float* __restrict__ h, const float* __restrict__ a_src, const float* __restrict__ a_dst,
    const int* __restrict__ offs, const int* __restrict__ csr, const float* __restrict__ b1,
    float* __restrict__ h1, int n) {
  int wid = (int)(((size_t)blockIdx.x * blockDim.x + threadIdx.x) >> 6);
  if (wid >= n) return;
  int lane = threadIdx.x & 63;
  int base = offs[wid];
  int deg = offs[wid + 1] - base;
  int hl = lane >> 4;
  int c0 = lane * 4;

  float4 adv = *(const float4*)(a_dst + wid * 4);
  float m0 = -1e30f, m1 = -1e30f, m2 = -1e30f, m3 = -1e30f;
  for (int e2 = lane; e2 < deg; e2 += 64) {
    int s = csr[base + e2];
    float4 sv = *(const float4*)(a_src + s * 4);
    float v0 = sv.x + adv.x; v0 = v0 > 0.f ? v0 : 0.2f * v0;
    float v1 = sv.y + adv.y; v1 = v1 > 0.f ? v1 : 0.2f * v1;
    float v2 = sv.z + adv.z; v2 = v2 > 0.f ? v2 : 0.2f * v2;
    float v3 = sv.w + adv.w; v3 = v3 > 0.f ? v3 : 0.2f * v3;
    m0 = fmaxf(m0, v0); m1 = fmaxf(m1, v1); m2 = fmaxf(m2, v2); m3 = fmaxf(m3, v3);
  }
#pragma unroll
  for (int o = 32; o; o >>= 1) {
    m0 = fmaxf(m0, __shfl_xor(m0, o));
    m1 = fmaxf(m1, __shfl_xor(m1, o));
    m2 = fmaxf(m2, __shfl_xor(m2, o));
    m3 = fmaxf(m3, __shfl_xor(m3, o));
  }
  float mh = hl == 0 ? m0 : hl == 1 ? m1 : hl == 2 ? m2 : m3;
  float adh = hl == 0 ? adv.x : hl == 1 ? adv.y : hl == 2 ? adv.z : adv.w;

  float denom = 0.f, acc0 = 0.f, acc1 = 0.f, acc2 = 0.f, acc3 = 0.f;
  for (int e2 = 0; e2 < deg; ++e2) {
    int s = csr[base + e2];
    float av = a_src[s * 4 + hl] + adh;
    av = av > 0.f ? av : 0.2f * av;
    float ea = __expf(av - mh);
    denom += ea;
    float4 hv = *(const float4*)(h + (size_t)s * 256 + c0);
    acc0 += ea * hv.x; acc1 += ea * hv.y; acc2 += ea * hv.z; acc3 += ea * hv.w;
  }
  float inv = 1.f / (denom + 1e-16f);
  float4 bb = *(const float4*)(b1 + c0);
  float4 o4;
  o4.x = fmaxf(acc0 * inv + bb.x, 0.f);
  o4.y = fmaxf(acc1 * inv + bb.y, 0.f);
  o4.z = fmaxf(acc2 * inv + bb.z, 0.f);
  o4.w = fmaxf(acc3 * inv + bb.w, 0.f);
  *(float4*)(h1 + (size_t)wid * 256 + c0) = o4;
}

// ---------- GCN aggregate: one wave per dst node ----------
__global__ __launch_bounds__(256) void gcn_aggregate(
    const float* __restrict__ h2, const int* __restrict__ offs, const int* __restrict__ csr,
    const float* __restrict__ dinv, const float* __restrict__ b2,
    float* __restrict__ out2, int n) {
  int wid = (int)(((size_t)blockIdx.x * blockDim.x + threadIdx.x) >> 6);
  if (wid >= n) return;
  int lane = threadIdx.x & 63;
  int base = offs[wid];
  int deg = offs[wid + 1] - base;
  int c0 = lane * 4;
  float dn = dinv[wid];
  float a0 = 0.f, a1 = 0.f, a2 = 0.f, a3 = 0.f;
  for (int e2 = 0; e2 < deg; ++e2) {
    int s = csr[base + e2];
    float wgt = dinv[s] * dn;
    float4 hv = *(const float4*)(h2 + (size_t)s * 256 + c0);
    a0 += wgt * hv.x; a1 += wgt * hv.y; a2 += wgt * hv.z; a3 += wgt * hv.w;
  }
  float4 bb = *(const float4*)(b2 + c0);
  float4 o4;
  o4.x = a0 + bb.x; o4.y = a1 + bb.y; o4.z = a2 + bb.z; o4.w = a3 + bb.w;
  *(float4*)(out2 + (size_t)wid * 256 + c0) = o4;
}

// ---------- mean pool over sorted batch ----------
__global__ __launch_bounds__(256) void pool_kernel(
    const float* __restrict__ out2, const int* __restrict__ batch, float* __restrict__ out, int n) {
  __shared__ int sb[2];
  int g = blockIdx.x;
  int t = threadIdx.x;
  if (t < 2) {
    int target = g + t;
    int lo = 0, hi = n;
    while (lo < hi) {
      int mid = (lo + hi) >> 1;
      if (batch[mid] < target) lo = mid + 1; else hi = mid;
    }
    sb[t] = lo;
  }
  __syncthreads();
  int start = sb[0], end = sb[1];
  int cnt = end - start;
  float acc = 0.f;
  for (int i = start; i < end; ++i) acc += out2[(size_t)i * 256 + t];
  out[g * 256 + t] = acc / fmaxf((float)cnt, 1.0f);
}

extern "C" void kernel_launch(void* const* d_in, const int* in_sizes, int n_in,
                              void* d_out, int out_size, void* d_ws, size_t ws_size,
                              hipStream_t stream) {
  const float* x = (const float*)d_in[0];
  const int* ei = (const int*)d_in[1];
  const int* batch = (const int*)d_in[2];
  const float* W1 = (const float*)d_in[3];
  const float* att_s = (const float*)d_in[4];
  const float* att_d = (const float*)d_in[5];
  const float* b1 = (const float*)d_in[6];
  const float* W2 = (const float*)d_in[7];
  const float* b2 = (const float*)d_in[8];
  float* out = (float*)d_out;

  const int n = N_NODES;
  const int e = in_sizes[1] / 2;
  const int* esrc = ei;
  const int* edst = ei + e;

  char* p = (char*)d_ws;
  size_t off_ = 0;
  auto alloc = [&](size_t b) -> void* {
    void* r = p + off_;
    off_ = (off_ + b + 255) & ~(size_t)255;
    return r;
  };
  __hip_bfloat16* xb = (__hip_bfloat16*)alloc((size_t)n * 512 * 2);
  float* h = (float*)alloc((size_t)n * 256 * 4);
  float* h1 = (float*)alloc((size_t)n * 256 * 4);
  float* asrc = (float*)alloc((size_t)n * 4 * 4);
  float* adst = (float*)alloc((size_t)n * 4 * 4);
  int* cnt = (int*)alloc((size_t)n * 4);
  int* offs = (int*)alloc((size_t)(n + 1) * 4);
  int* cur = (int*)alloc((size_t)n * 4);
  int* csr = (int*)alloc((size_t)(e + n) * 4);
  float* dinv = (float*)alloc((size_t)n * 4);
  __hip_bfloat16* W1t = (__hip_bfloat16*)alloc(512 * 256 * 2);
  __hip_bfloat16* W2t = (__hip_bfloat16*)alloc(256 * 256 * 2);
  __hip_bfloat16* h1b = xb;  // reuse (x dead after GEMM1)
  float* h2 = h;             // reuse (h dead after GAT)
  float* out2 = h1;          // reuse (h1 dead after cvt to bf16)

  // conversions + zero
  cvt_f32_bf16<<<(n * 512 / 4 + 255) / 256, 256, 0, stream>>>(x, xb, n * 512);
  cvt_transpose<<<(512 * 256 + 255) / 256, 256, 0, stream>>>(W1, W1t, 512, 256);
  cvt_transpose<<<(256 * 256 + 255) / 256, 256, 0, stream>>>(W2, W2t, 256, 256);
  zero_i32<<<(n + 255) / 256, 256, 0, stream>>>(cnt, n);

  // GEMM1: h = x @ W1   [n,512]x[512,256]
  dim3 g1((n + 127) / 128, 2);
  gemm_bt<<<g1, 256, 0, stream>>>(xb, W1t, h, n, 256, 512);

  // attention logits
  att_kernel<<<(n + 3) / 4, 256, 0, stream>>>(h, att_s, att_d, asrc, adst, n);

  // CSR by dst (with self loops)
  count_deg<<<(e + n + 255) / 256, 256, 0, stream>>>(edst, cnt, e, n);
  scan_kernel<<<1, 1024, 0, stream>>>(cnt, offs, cur, n);
  scatter_edges<<<(e + n + 255) / 256, 256, 0, stream>>>(esrc, edst, cur, csr, e, n);
  compute_dinv<<<(n + 255) / 256, 256, 0, stream>>>(cnt, dinv, n);

  // GAT aggregate + relu
  gat_aggregate<<<(n + 3) / 4, 256, 0, stream>>>(h, asrc, adst, offs, csr, b1, h1, n);

  // h1 -> bf16
  cvt_f32_bf16<<<(n * 256 / 4 + 255) / 256, 256, 0, stream>>>(h1, h1b, n * 256);

  // GEMM2: h2 = h1 @ W2  [n,256]x[256,256]
  gemm_bt<<<g1, 256, 0, stream>>>(h1b, W2t, h2, n, 256, 256);

  // GCN aggregate
  gcn_aggregate<<<(n + 3) / 4, 256, 0, stream>>>(h2, offs, csr, dinv, b2, out2, n);

  // mean pool
  pool_kernel<<<N_GROUPS, 256, 0, stream>>>(out2, batch, out, n);
}

// Round 2
// 751.985 us; speedup vs baseline: 1.2506x; 1.2506x over previous
//
#include <hip/hip_runtime.h>
#include <hip/hip_bf16.h>

#define N_NODES 50000
#define N_GROUPS 50

typedef unsigned short u16x8 __attribute__((ext_vector_type(8)));
typedef unsigned short u16x4 __attribute__((ext_vector_type(4)));
typedef __bf16 bf16x8 __attribute__((ext_vector_type(8)));
typedef float f32x4 __attribute__((ext_vector_type(4)));

__device__ __forceinline__ float bf2f(unsigned short u) {
  union { unsigned int i; float f; } v; v.i = ((unsigned int)u) << 16; return v.f;
}
__device__ __forceinline__ unsigned short f2bf(float f) {
  __hip_bfloat16 b = __float2bfloat16(f);
  return *(unsigned short*)&b;
}

// ---------- conversion kernels ----------
__global__ void cvt_f32_bf16(const float* __restrict__ in, __hip_bfloat16* __restrict__ out, int n) {
  int i = blockIdx.x * blockDim.x + threadIdx.x;
  int base = i * 4;
  if (base + 3 < n) {
    float4 v = *(const float4*)(in + base);
    out[base + 0] = __float2bfloat16(v.x);
    out[base + 1] = __float2bfloat16(v.y);
    out[base + 2] = __float2bfloat16(v.z);
    out[base + 3] = __float2bfloat16(v.w);
  } else {
    for (int k = base; k < n; ++k) out[k] = __float2bfloat16(in[k]);
  }
}

// out[c][r] = in[r][c]  (store transposed, bf16)
__global__ void cvt_transpose(const float* __restrict__ in, __hip_bfloat16* __restrict__ out, int R, int C) {
  int i = blockIdx.x * blockDim.x + threadIdx.x;
  if (i < R * C) {
    int r = i / C, c = i % C;
    out[(size_t)c * R + r] = __float2bfloat16(in[i]);
  }
}

// ---------- CSR build ----------
__global__ void count_deg(const int* __restrict__ dst, int* __restrict__ cnt, int e, int n) {
  int i = blockIdx.x * blockDim.x + threadIdx.x;
  if (i < e + n) {
    int d = (i < e) ? dst[i] : (i - e);   // self loops appended
    atomicAdd(&cnt[d], 1);
  }
}

__global__ void scan_kernel(const int* __restrict__ cnt, int* __restrict__ offs,
                            int* __restrict__ cur, int n) {
  __shared__ int part[1024];
  int tid = threadIdx.x;
  int chunk = (n + 1023) >> 10;
  int b = tid * chunk;
  int epos = b + chunk; if (epos > n) epos = n;
  int s = 0;
  for (int i = b; i < epos; ++i) s += cnt[i];
  part[tid] = s;
  __syncthreads();
  for (int d = 1; d < 1024; d <<= 1) {
    int v = 0;
    if (tid >= d) v = part[tid - d];
    __syncthreads();
    part[tid] += v;
    __syncthreads();
  }
  int base = part[tid] - s;  // exclusive prefix
  for (int i = b; i < epos; ++i) { offs[i] = base; cur[i] = base; base += cnt[i]; }
  if (b < n && epos == n) offs[n] = base;
}

__global__ void scatter_edges(const int* __restrict__ src, const int* __restrict__ dst,
                              int* __restrict__ cur, int* __restrict__ csr, int e, int n) {
  int i = blockIdx.x * blockDim.x + threadIdx.x;
  if (i < e + n) {
    int s, d;
    if (i < e) { s = src[i]; d = dst[i]; } else { s = i - e; d = i - e; }
    int pos = atomicAdd(&cur[d], 1);
    csr[pos] = s;
  }
}

__global__ void compute_dinv(const int* __restrict__ cnt, float* __restrict__ dinv, int n) {
  int i = blockIdx.x * blockDim.x + threadIdx.x;
  if (i < n) {
    int c = cnt[i]; if (c < 1) c = 1;
    dinv[i] = 1.0f / sqrtf((float)c);
  }
}

// ---------- bf16 MFMA GEMM: C[M][Nc] = A[M][K] * Bt[Nc][K]^T ----------
template <bool OUTBF>
__global__ __launch_bounds__(256) void gemm_bt(
    const __hip_bfloat16* __restrict__ A, const __hip_bfloat16* __restrict__ Bt,
    void* __restrict__ Cv, int M, int Nc, int K) {
  __shared__ __hip_bfloat16 Ash[128][40];
  __shared__ __hip_bfloat16 Bsh[128][40];
  const int tid = threadIdx.x;
  const int lane = tid & 63;
  const int w = tid >> 6;
  const int wr = (w >> 1) * 64, wc = (w & 1) * 64;
  const int row0 = blockIdx.x * 128, col0 = blockIdx.y * 128;
  const int sr = tid >> 2;
  const int sc = (tid & 3) * 8;

  f32x4 zero4 = {0.f, 0.f, 0.f, 0.f};
  f32x4 acc[4][4];
#pragma unroll
  for (int i = 0; i < 4; i++)
#pragma unroll
    for (int j = 0; j < 4; j++) acc[i][j] = zero4;

  u16x8 z8 = {0, 0, 0, 0, 0, 0, 0, 0};

  auto loadA = [&](int r, int k) -> u16x8 {
    int rr = row0 + r;
    if (rr < M) return *(const u16x8*)(A + (size_t)rr * K + k + sc);
    return z8;
  };
  auto loadB = [&](int r, int k) -> u16x8 {
    int rr = col0 + r;
    if (rr < Nc) return *(const u16x8*)(Bt + (size_t)rr * K + k + sc);
    return z8;
  };

  u16x8 ar0 = loadA(sr, 0), ar1 = loadA(sr + 64, 0);
  u16x8 br0 = loadB(sr, 0), br1 = loadB(sr + 64, 0);

  const int lrow = lane & 15;
  const int lk = (lane >> 4) * 8;

  for (int kt = 0; kt < K; kt += 32) {
    __syncthreads();
    *(u16x8*)&Ash[sr][sc] = ar0;
    *(u16x8*)&Ash[sr + 64][sc] = ar1;
    *(u16x8*)&Bsh[sr][sc] = br0;
    *(u16x8*)&Bsh[sr + 64][sc] = br1;
    __syncthreads();
    int kn = kt + 32;
    if (kn < K) {
      ar0 = loadA(sr, kn); ar1 = loadA(sr + 64, kn);
      br0 = loadB(sr, kn); br1 = loadB(sr + 64, kn);
    }
    bf16x8 av[4], bv[4];
#pragma unroll
    for (int i = 0; i < 4; i++) av[i] = *(const bf16x8*)&Ash[wr + i * 16 + lrow][lk];
#pragma unroll
    for (int j = 0; j < 4; j++) bv[j] = *(const bf16x8*)&Bsh[wc + j * 16 + lrow][lk];
#pragma unroll
    for (int i = 0; i < 4; i++)
#pragma unroll
      for (int j = 0; j < 4; j++)
        acc[i][j] = __builtin_amdgcn_mfma_f32_16x16x32_bf16(av[i], bv[j], acc[i][j], 0, 0, 0);
  }

#pragma unroll
  for (int i = 0; i < 4; i++) {
#pragma unroll
    for (int r = 0; r < 4; r++) {
      int rr = row0 + wr + i * 16 + (lane >> 4) * 4 + r;
      if (rr < M) {
#pragma unroll
        for (int j = 0; j < 4; j++) {
          int cc = col0 + wc + j * 16 + (lane & 15);
          if (cc < Nc) {
            if constexpr (OUTBF) {
              ((__hip_bfloat16*)Cv)[(size_t)rr * Nc + cc] = __float2bfloat16(acc[i][j][r]);
            } else {
              ((float*)Cv)[(size_t)rr * Nc + cc] = acc[i][j][r];
            }
          }
        }
      }
    }
  }
}

// ---------- per-node attention logits: a_src[n][h], a_dst[n][h] (h in bf16) ----------
__global__ __launch_bounds__(256) void att_kernel(
    const __hip_bfloat16* __restrict__ h, const float* __restrict__ att_s, const float* __restrict__ att_d,
    float* __restrict__ a_src, float* __restrict__ a_dst, int n) {
  int wid = (int)(((size_t)blockIdx.x * blockDim.x + threadIdx.x) >> 6);
  if (wid >= n) return;
  int lane = threadIdx.x & 63;
  int c0 = lane * 4;
  u16x4 hv = *(const u16x4*)(h + (size_t)wid * 256 + c0);
  float h0 = bf2f(hv[0]), h1_ = bf2f(hv[1]), h2_ = bf2f(hv[2]), h3 = bf2f(hv[3]);
  float4 as = *(const float4*)(att_s + c0);
  float4 ad = *(const float4*)(att_d + c0);
  float ds_ = h0 * as.x + h1_ * as.y + h2_ * as.z + h3 * as.w;
  float dd_ = h0 * ad.x + h1_ * ad.y + h2_ * ad.z + h3 * ad.w;
#pragma unroll
  for (int m = 1; m < 16; m <<= 1) {
    ds_ += __shfl_xor(ds_, m);
    dd_ += __shfl_xor(dd_, m);
  }
  if ((lane & 15) == 0) {
    a_src[wid * 4 + (lane >> 4)] = ds_;
    a_dst[wid * 4 + (lane >> 4)] = dd_;
  }
}

// ---------- GAT aggregate: one wave per dst node (bf16 h in, bf16 h1 out) ----------
__global__ __launch_bounds__(256) void gat_aggregate(
    const __hip_bfloat16* __restrict__ h, const float* __restrict__ a_src, const float* __restrict__ a_dst,
    const int* __restrict__ offs, const int* __restrict__ csr, const float* __restrict__ b1,
    __hip_bfloat16* __restrict__ h1, int n) {
  int wid = (int)(((size_t)blockIdx.x * blockDim.x + threadIdx.x) >> 6);
  if (wid >= n) return;
  int lane = threadIdx.x & 63;
  int base = offs[wid];
  int deg = offs[wid + 1] - base;
  int hl = lane >> 4;
  int c0 = lane * 4;

  float4 adv = *(const float4*)(a_dst + wid * 4);
  float m0 = -1e30f, m1 = -1e30f, m2 = -1e30f, m3 = -1e30f;
  for (int e2 = lane; e2 < deg; e2 += 64) {
    int s = csr[base + e2];
    float4 sv = *(const float4*)(a_src + s * 4);
    float v0 = sv.x + adv.x; v0 = v0 > 0.f ? v0 : 0.2f * v0;
    float v1 = sv.y + adv.y; v1 = v1 > 0.f ? v1 : 0.2f * v1;
    float v2 = sv.z + adv.z; v2 = v2 > 0.f ? v2 : 0.2f * v2;
    float v3 = sv.w + adv.w; v3 = v3 > 0.f ? v3 : 0.2f * v3;
    m0 = fmaxf(m0, v0); m1 = fmaxf(m1, v1); m2 = fmaxf(m2, v2); m3 = fmaxf(m3, v3);
  }
#pragma unroll
  for (int o = 32; o; o >>= 1) {
    m0 = fmaxf(m0, __shfl_xor(m0, o));
    m1 = fmaxf(m1, __shfl_xor(m1, o));
    m2 = fmaxf(m2, __shfl_xor(m2, o));
    m3 = fmaxf(m3, __shfl_xor(m3, o));
  }
  float mh = hl == 0 ? m0 : hl == 1 ? m1 : hl == 2 ? m2 : m3;
  float adh = hl == 0 ? adv.x : hl == 1 ? adv.y : hl == 2 ? adv.z : adv.w;

  float denom = 0.f, acc0 = 0.f, acc1 = 0.f, acc2 = 0.f, acc3 = 0.f;
  for (int e2 = 0; e2 < deg; ++e2) {
    int s = csr[base + e2];
    float av = a_src[s * 4 + hl] + adh;
    av = av > 0.f ? av : 0.2f * av;
    float ea = __expf(av - mh);
    denom += ea;
    u16x4 hv = *(const u16x4*)(h + (size_t)s * 256 + c0);
    acc0 += ea * bf2f(hv[0]); acc1 += ea * bf2f(hv[1]);
    acc2 += ea * bf2f(hv[2]); acc3 += ea * bf2f(hv[3]);
  }
  float inv = 1.f / (denom + 1e-16f);
  float4 bb = *(const float4*)(b1 + c0);
  u16x4 o4;
  o4[0] = f2bf(fmaxf(acc0 * inv + bb.x, 0.f));
  o4[1] = f2bf(fmaxf(acc1 * inv + bb.y, 0.f));
  o4[2] = f2bf(fmaxf(acc2 * inv + bb.z, 0.f));
  o4[3] = f2bf(fmaxf(acc3 * inv + bb.w, 0.f));
  *(u16x4*)(h1 + (size_t)wid * 256 + c0) = o4;
}

// ---------- GCN aggregate: one wave per dst node (bf16 h2 in, f32 out) ----------
__global__ __launch_bounds__(256) void gcn_aggregate(
    const __hip_bfloat16* __restrict__ h2, const int* __restrict__ offs, const int* __restrict__ csr,
    const float* __restrict__ dinv, const float* __restrict__ b2,
    float* __restrict__ out2, int n) {
  int wid = (int)(((size_t)blockIdx.x * blockDim.x + threadIdx.x) >> 6);
  if (wid >= n) return;
  int lane = threadIdx.x & 63;
  int base = offs[wid];
  int deg = offs[wid + 1] - base;
  int c0 = lane * 4;
  float dn = dinv[wid];
  float a0 = 0.f, a1 = 0.f, a2 = 0.f, a3 = 0.f;
  for (int e2 = 0; e2 < deg; ++e2) {
    int s = csr[base + e2];
    float wgt = dinv[s] * dn;
    u16x4 hv = *(const u16x4*)(h2 + (size_t)s * 256 + c0);
    a0 += wgt * bf2f(hv[0]); a1 += wgt * bf2f(hv[1]);
    a2 += wgt * bf2f(hv[2]); a3 += wgt * bf2f(hv[3]);
  }
  float4 bb = *(const float4*)(b2 + c0);
  float4 o4;
  o4.x = a0 + bb.x; o4.y = a1 + bb.y; o4.z = a2 + bb.z; o4.w = a3 + bb.w;
  *(float4*)(out2 + (size_t)wid * 256 + c0) = o4;
}

// ---------- mean pool, stage 1: per-block partial sums with boundary flush ----------
__global__ __launch_bounds__(256) void pool_partial(
    const float* __restrict__ out2, const int* __restrict__ batch,
    float* __restrict__ accum, int n) {
  int t = threadIdx.x;
  int start = blockIdx.x * 256;
  if (start >= n) return;
  int end = start + 256; if (end > n) end = n;
  int curg = batch[start];
  float acc = 0.f;
  for (int i = start; i < end; ++i) {
    int g = batch[i];
    if (g != curg) {
      atomicAdd(&accum[curg * 256 + t], acc);
      acc = 0.f; curg = g;
    }
    acc += out2[(size_t)i * 256 + t];
  }
  atomicAdd(&accum[curg * 256 + t], acc);
}

// ---------- mean pool, stage 2: divide by group count ----------
__global__ __launch_bounds__(256) void pool_finalize(
    const float* __restrict__ accum, const int* __restrict__ batch,
    float* __restrict__ out, int n) {
  __shared__ int sb[2];
  int g = blockIdx.x;
  int t = threadIdx.x;
  if (t < 2) {
    int target = g + t;
    int lo = 0, hi = n;
    while (lo < hi) {
      int mid = (lo + hi) >> 1;
      if (batch[mid] < target) lo = mid + 1; else hi = mid;
    }
    sb[t] = lo;
  }
  __syncthreads();
  int cnt = sb[1] - sb[0];
  out[g * 256 + t] = accum[g * 256 + t] / fmaxf((float)cnt, 1.0f);
}

extern "C" void kernel_launch(void* const* d_in, const int* in_sizes, int n_in,
                              void* d_out, int out_size, void* d_ws, size_t ws_size,
                              hipStream_t stream) {
  const float* x = (const float*)d_in[0];
  const int* ei = (const int*)d_in[1];
  const int* batch = (const int*)d_in[2];
  const float* W1 = (const float*)d_in[3];
  const float* att_s = (const float*)d_in[4];
  const float* att_d = (const float*)d_in[5];
  const float* b1 = (const float*)d_in[6];
  const float* W2 = (const float*)d_in[7];
  const float* b2 = (const float*)d_in[8];
  float* out = (float*)d_out;

  const int n = N_NODES;
  const int e = in_sizes[1] / 2;
  const int* esrc = ei;
  const int* edst = ei + e;

  char* p = (char*)d_ws;
  size_t off_ = 0;
  auto alloc = [&](size_t b) -> void* {
    void* r = p + off_;
    off_ = (off_ + b + 255) & ~(size_t)255;
    return r;
  };
  __hip_bfloat16* xb = (__hip_bfloat16*)alloc((size_t)n * 512 * 2);   // 51.2 MB
  __hip_bfloat16* hb = (__hip_bfloat16*)alloc((size_t)n * 256 * 2);   // 25.6 MB
  __hip_bfloat16* h1b = (__hip_bfloat16*)alloc((size_t)n * 256 * 2);  // 25.6 MB
  float* out2 = (float*)alloc((size_t)n * 256 * 4);                   // 51.2 MB
  float* asrc = (float*)alloc((size_t)n * 4 * 4);
  float* adst = (float*)alloc((size_t)n * 4 * 4);
  int* cnt = (int*)alloc((size_t)n * 4);
  int* offs = (int*)alloc((size_t)(n + 1) * 4);
  int* cur = (int*)alloc((size_t)n * 4);
  int* csr = (int*)alloc((size_t)(e + n) * 4);
  float* dinv = (float*)alloc((size_t)n * 4);
  __hip_bfloat16* W1t = (__hip_bfloat16*)alloc(512 * 256 * 2);
  __hip_bfloat16* W2t = (__hip_bfloat16*)alloc(256 * 256 * 2);
  float* accum = (float*)alloc((size_t)N_GROUPS * 256 * 4);
  // reuse: x/xb dead after GEMM1 — h2 (bf16) lives in xb's region
  __hip_bfloat16* h2b = xb;

  // conversions + zeroing
  cvt_f32_bf16<<<(n * 512 / 4 + 255) / 256, 256, 0, stream>>>(x, xb, n * 512);
  cvt_transpose<<<(512 * 256 + 255) / 256, 256, 0, stream>>>(W1, W1t, 512, 256);
  cvt_transpose<<<(256 * 256 + 255) / 256, 256, 0, stream>>>(W2, W2t, 256, 256);
  hipMemsetAsync(cnt, 0, (size_t)n * 4, stream);
  hipMemsetAsync(accum, 0, (size_t)N_GROUPS * 256 * 4, stream);

  // GEMM1: h = x @ W1   [n,512]x[512,256] -> bf16
  dim3 g1((n + 127) / 128, 2);
  gemm_bt<true><<<g1, 256, 0, stream>>>(xb, W1t, hb, n, 256, 512);

  // attention logits
  att_kernel<<<(n + 3) / 4, 256, 0, stream>>>(hb, att_s, att_d, asrc, adst, n);

  // CSR by dst (with self loops)
  count_deg<<<(e + n + 255) / 256, 256, 0, stream>>>(edst, cnt, e, n);
  scan_kernel<<<1, 1024, 0, stream>>>(cnt, offs, cur, n);
  scatter_edges<<<(e + n + 255) / 256, 256, 0, stream>>>(esrc, edst, cur, csr, e, n);
  compute_dinv<<<(n + 255) / 256, 256, 0, stream>>>(cnt, dinv, n);

  // GAT aggregate + bias + relu -> bf16 h1
  gat_aggregate<<<(n + 3) / 4, 256, 0, stream>>>(hb, asrc, adst, offs, csr, b1, h1b, n);

  // GEMM2: h2 = h1 @ W2  [n,256]x[256,256] -> bf16
  gemm_bt<true><<<g1, 256, 0, stream>>>(h1b, W2t, h2b, n, 256, 256);

  // GCN aggregate -> f32 out2
  gcn_aggregate<<<(n + 3) / 4, 256, 0, stream>>>(h2b, offs, csr, dinv, b2, out2, n);

  // mean pool (two-stage)
  pool_partial<<<(n + 255) / 256, 256, 0, stream>>>(out2, batch, accum, n);
  pool_finalize<<<N_GROUPS, 256, 0, stream>>>(accum, batch, out, n);
}

// Round 3
// 680.634 us; speedup vs baseline: 1.3817x; 1.1048x over previous
//
#include <hip/hip_runtime.h>
#include <hip/hip_bf16.h>

#define N_NODES 50000
#define N_GROUPS 50

typedef unsigned short u16x8 __attribute__((ext_vector_type(8)));
typedef unsigned short u16x4 __attribute__((ext_vector_type(4)));
typedef __bf16 bf16x8 __attribute__((ext_vector_type(8)));
typedef float f32x4 __attribute__((ext_vector_type(4)));

__device__ __forceinline__ float bf2f(unsigned short u) {
  union { unsigned int i; float f; } v; v.i = ((unsigned int)u) << 16; return v.f;
}
__device__ __forceinline__ unsigned short f2bf(float f) {
  __hip_bfloat16 b = __float2bfloat16(f);
  return *(unsigned short*)&b;
}
// order-preserving float<->uint keys for atomicMax
__device__ __forceinline__ unsigned fkey(float f) {
  unsigned b = __float_as_uint(f);
  return (b & 0x80000000u) ? ~b : (b | 0x80000000u);
}
__device__ __forceinline__ float keyf(unsigned k) {
  unsigned b = (k & 0x80000000u) ? (k & 0x7fffffffu) : ~k;
  return __uint_as_float(b);
}

// out[c][r] = in[r][c]  (store transposed, bf16)
__global__ void cvt_transpose(const float* __restrict__ in, __hip_bfloat16* __restrict__ out, int R, int C) {
  int i = blockIdx.x * blockDim.x + threadIdx.x;
  if (i < R * C) {
    int r = i / C, c = i % C;
    out[(size_t)c * R + r] = __float2bfloat16(in[i]);
  }
}

// ---------- CSR build ----------
__global__ void count_deg(const int* __restrict__ dst, int* __restrict__ cnt, int e, int n) {
  int i = blockIdx.x * blockDim.x + threadIdx.x;
  if (i < e + n) {
    int d = (i < e) ? dst[i] : (i - e);   // self loops appended
    atomicAdd(&cnt[d], 1);
  }
}

__global__ void scan_kernel(const int* __restrict__ cnt, int* __restrict__ offs,
                            int* __restrict__ cur, int n) {
  __shared__ int part[1024];
  int tid = threadIdx.x;
  int chunk = (n + 1023) >> 10;
  int b = tid * chunk;
  int epos = b + chunk; if (epos > n) epos = n;
  int s = 0;
  for (int i = b; i < epos; ++i) s += cnt[i];
  part[tid] = s;
  __syncthreads();
  for (int d = 1; d < 1024; d <<= 1) {
    int v = 0;
    if (tid >= d) v = part[tid - d];
    __syncthreads();
    part[tid] += v;
    __syncthreads();
  }
  int base = part[tid] - s;  // exclusive prefix
  for (int i = b; i < epos; ++i) { offs[i] = base; cur[i] = base; base += cnt[i]; }
  if (b < n && epos == n) offs[n] = base;
}

__global__ void scatter_edges(const int* __restrict__ src, const int* __restrict__ dst,
                              int* __restrict__ cur, int* __restrict__ csr, int e, int n) {
  int i = blockIdx.x * blockDim.x + threadIdx.x;
  if (i < e + n) {
    int s, d;
    if (i < e) { s = src[i]; d = dst[i]; } else { s = i - e; d = i - e; }
    int pos = atomicAdd(&cur[d], 1);
    csr[pos] = s;
  }
}

__global__ void compute_dinv(const int* __restrict__ cnt, float* __restrict__ dinv, int n) {
  int i = blockIdx.x * blockDim.x + threadIdx.x;
  if (i < n) {
    int c = cnt[i]; if (c < 1) c = 1;
    dinv[i] = 1.0f / sqrtf((float)c);
  }
}

// ---------- bf16 MFMA GEMM: C[M][Nc] = A[M][K] * Bt[Nc][K]^T ----------
template <bool AF32, bool OUTBF>
__global__ __launch_bounds__(256) void gemm_bt(
    const void* __restrict__ Av, const __hip_bfloat16* __restrict__ Bt,
    void* __restrict__ Cv, int M, int Nc, int K) {
  __shared__ __hip_bfloat16 Ash[128][40];
  __shared__ __hip_bfloat16 Bsh[128][40];
  const int tid = threadIdx.x;
  const int lane = tid & 63;
  const int w = tid >> 6;
  const int wr = (w >> 1) * 64, wc = (w & 1) * 64;
  const int row0 = blockIdx.x * 128, col0 = blockIdx.y * 128;
  const int sr = tid >> 2;
  const int sc = (tid & 3) * 8;

  f32x4 zero4 = {0.f, 0.f, 0.f, 0.f};
  f32x4 acc[4][4];
#pragma unroll
  for (int i = 0; i < 4; i++)
#pragma unroll
    for (int j = 0; j < 4; j++) acc[i][j] = zero4;

  u16x8 z8 = {0, 0, 0, 0, 0, 0, 0, 0};

  auto loadA = [&](int r, int k) -> u16x8 {
    int rr = row0 + r;
    if (rr >= M) return z8;
    if constexpr (AF32) {
      const float* ap = (const float*)Av + (size_t)rr * K + k + sc;
      float4 f0 = *(const float4*)ap;
      float4 f1 = *(const float4*)(ap + 4);
      u16x8 o;
      o[0] = f2bf(f0.x); o[1] = f2bf(f0.y); o[2] = f2bf(f0.z); o[3] = f2bf(f0.w);
      o[4] = f2bf(f1.x); o[5] = f2bf(f1.y); o[6] = f2bf(f1.z); o[7] = f2bf(f1.w);
      return o;
    } else {
      return *(const u16x8*)((const __hip_bfloat16*)Av + (size_t)rr * K + k + sc);
    }
  };
  auto loadB = [&](int r, int k) -> u16x8 {
    int rr = col0 + r;
    if (rr < Nc) return *(const u16x8*)(Bt + (size_t)rr * K + k + sc);
    return z8;
  };

  u16x8 ar0 = loadA(sr, 0), ar1 = loadA(sr + 64, 0);
  u16x8 br0 = loadB(sr, 0), br1 = loadB(sr + 64, 0);

  const int lrow = lane & 15;
  const int lk = (lane >> 4) * 8;

  for (int kt = 0; kt < K; kt += 32) {
    __syncthreads();
    *(u16x8*)&Ash[sr][sc] = ar0;
    *(u16x8*)&Ash[sr + 64][sc] = ar1;
    *(u16x8*)&Bsh[sr][sc] = br0;
    *(u16x8*)&Bsh[sr + 64][sc] = br1;
    __syncthreads();
    int kn = kt + 32;
    if (kn < K) {
      ar0 = loadA(sr, kn); ar1 = loadA(sr + 64, kn);
      br0 = loadB(sr, kn); br1 = loadB(sr + 64, kn);
    }
    bf16x8 av[4], bv[4];
#pragma unroll
    for (int i = 0; i < 4; i++) av[i] = *(const bf16x8*)&Ash[wr + i * 16 + lrow][lk];
#pragma unroll
    for (int j = 0; j < 4; j++) bv[j] = *(const bf16x8*)&Bsh[wc + j * 16 + lrow][lk];
#pragma unroll
    for (int i = 0; i < 4; i++)
#pragma unroll
      for (int j = 0; j < 4; j++)
        acc[i][j] = __builtin_amdgcn_mfma_f32_16x16x32_bf16(av[i], bv[j], acc[i][j], 0, 0, 0);
  }

#pragma unroll
  for (int i = 0; i < 4; i++) {
#pragma unroll
    for (int r = 0; r < 4; r++) {
      int rr = row0 + wr + i * 16 + (lane >> 4) * 4 + r;
      if (rr < M) {
#pragma unroll
        for (int j = 0; j < 4; j++) {
          int cc = col0 + wc + j * 16 + (lane & 15);
          if (cc < Nc) {
            if constexpr (OUTBF) {
              ((__hip_bfloat16*)Cv)[(size_t)rr * Nc + cc] = __float2bfloat16(acc[i][j][r]);
            } else {
              ((float*)Cv)[(size_t)rr * Nc + cc] = acc[i][j][r];
            }
          }
        }
      }
    }
  }
}

// ---------- per-node attention logits: a_src[n][h], a_dst[n][h] (h in bf16) ----------
__global__ __launch_bounds__(256) void att_kernel(
    const __hip_bfloat16* __restrict__ h, const float* __restrict__ att_s, const float* __restrict__ att_d,
    float* __restrict__ a_src, float* __restrict__ a_dst, int n) {
  int wid = (int)(((size_t)blockIdx.x * blockDim.x + threadIdx.x) >> 6);
  if (wid >= n) return;
  int lane = threadIdx.x & 63;
  int c0 = lane * 4;
  u16x4 hv = *(const u16x4*)(h + (size_t)wid * 256 + c0);
  float h0 = bf2f(hv[0]), h1_ = bf2f(hv[1]), h2_ = bf2f(hv[2]), h3 = bf2f(hv[3]);
  float4 as = *(const float4*)(att_s + c0);
  float4 ad = *(const float4*)(att_d + c0);
  float ds_ = h0 * as.x + h1_ * as.y + h2_ * as.z + h3 * as.w;
  float dd_ = h0 * ad.x + h1_ * ad.y + h2_ * ad.z + h3 * ad.w;
#pragma unroll
  for (int m = 1; m < 16; m <<= 1) {
    ds_ += __shfl_xor(ds_, m);
    dd_ += __shfl_xor(dd_, m);
  }
  if ((lane & 15) == 0) {
    a_src[wid * 4 + (lane >> 4)] = ds_;
    a_dst[wid * 4 + (lane >> 4)] = dd_;
  }
}

// ---------- global per-head maxes of a_src / a_dst ----------
__global__ __launch_bounds__(256) void att_max(
    const float* __restrict__ asrc, const float* __restrict__ adst,
    unsigned* __restrict__ gkey, int n) {
  float ms0 = -1e30f, ms1 = -1e30f, ms2 = -1e30f, ms3 = -1e30f;
  float md0 = -1e30f, md1 = -1e30f, md2 = -1e30f, md3 = -1e30f;
  for (int i = blockIdx.x * blockDim.x + threadIdx.x; i < n; i += gridDim.x * blockDim.x) {
    float4 s = *(const float4*)(asrc + (size_t)i * 4);
    float4 d = *(const float4*)(adst + (size_t)i * 4);
    ms0 = fmaxf(ms0, s.x); ms1 = fmaxf(ms1, s.y); ms2 = fmaxf(ms2, s.z); ms3 = fmaxf(ms3, s.w);
    md0 = fmaxf(md0, d.x); md1 = fmaxf(md1, d.y); md2 = fmaxf(md2, d.z); md3 = fmaxf(md3, d.w);
  }
#pragma unroll
  for (int o = 32; o; o >>= 1) {
    ms0 = fmaxf(ms0, __shfl_xor(ms0, o)); ms1 = fmaxf(ms1, __shfl_xor(ms1, o));
    ms2 = fmaxf(ms2, __shfl_xor(ms2, o)); ms3 = fmaxf(ms3, __shfl_xor(ms3, o));
    md0 = fmaxf(md0, __shfl_xor(md0, o)); md1 = fmaxf(md1, __shfl_xor(md1, o));
    md2 = fmaxf(md2, __shfl_xor(md2, o)); md3 = fmaxf(md3, __shfl_xor(md3, o));
  }
  if ((threadIdx.x & 63) == 0) {
    atomicMax(&gkey[0], fkey(ms0)); atomicMax(&gkey[1], fkey(ms1));
    atomicMax(&gkey[2], fkey(ms2)); atomicMax(&gkey[3], fkey(ms3));
    atomicMax(&gkey[4], fkey(md0)); atomicMax(&gkey[5], fkey(md1));
    atomicMax(&gkey[6], fkey(md2)); atomicMax(&gkey[7], fkey(md3));
  }
}

// ---------- GAT aggregate: one wave per dst node, 2 edges/load (half-wave split) ----------
__global__ __launch_bounds__(256) void gat_aggregate(
    const __hip_bfloat16* __restrict__ h, const float* __restrict__ a_src, const float* __restrict__ a_dst,
    const int* __restrict__ offs, const int* __restrict__ csr, const float* __restrict__ b1,
    const unsigned* __restrict__ gkey, __hip_bfloat16* __restrict__ h1, int n) {
  int wid = (int)(((size_t)blockIdx.x * blockDim.x + threadIdx.x) >> 6);
  if (wid >= n) return;
  int lane = threadIdx.x & 63;
  int half = lane >> 5;
  int l5 = lane & 31;
  int c0 = l5 * 8;          // 8 channels per lane, 32 lanes cover 256
  int hl = l5 >> 3;         // head = c0/64
  int base = offs[wid];
  int deg = offs[wid + 1] - base;

  float mh = keyf(gkey[hl]) + keyf(gkey[4 + hl]);
  mh = mh > 0.f ? mh : 0.2f * mh;           // lrelu of upper bound >= all alpha
  float adh = a_dst[wid * 4 + hl];

  float den = 0.f;
  float acc[8] = {0.f, 0.f, 0.f, 0.f, 0.f, 0.f, 0.f, 0.f};
  int P = deg >> 1;
  int i = 0;
  for (; i + 2 <= P; i += 2) {
    int sA = csr[base + 2 * i + half];
    int sB = csr[base + 2 * i + 2 + half];
    float aA = a_src[sA * 4 + hl];
    float aB = a_src[sB * 4 + hl];
    u16x8 rA = *(const u16x8*)(h + (size_t)sA * 256 + c0);
    u16x8 rB = *(const u16x8*)(h + (size_t)sB * 256 + c0);
    float vA = aA + adh; vA = vA > 0.f ? vA : 0.2f * vA;
    float vB = aB + adh; vB = vB > 0.f ? vB : 0.2f * vB;
    float eA = __expf(vA - mh);
    float eB = __expf(vB - mh);
    den += eA + eB;
#pragma unroll
    for (int ch = 0; ch < 8; ++ch) acc[ch] += eA * bf2f(rA[ch]) + eB * bf2f(rB[ch]);
  }
  if (i < P) {
    int sA = csr[base + 2 * i + half];
    float aA = a_src[sA * 4 + hl];
    u16x8 rA = *(const u16x8*)(h + (size_t)sA * 256 + c0);
    float vA = aA + adh; vA = vA > 0.f ? vA : 0.2f * vA;
    float eA = __expf(vA - mh);
    den += eA;
#pragma unroll
    for (int ch = 0; ch < 8; ++ch) acc[ch] += eA * bf2f(rA[ch]);
  }
  if ((deg & 1) && half == 0) {
    int sA = csr[base + deg - 1];
    float aA = a_src[sA * 4 + hl];
    u16x8 rA = *(const u16x8*)(h + (size_t)sA * 256 + c0);
    float vA = aA + adh; vA = vA > 0.f ? vA : 0.2f * vA;
    float eA = __expf(vA - mh);
    den += eA;
#pragma unroll
    for (int ch = 0; ch < 8; ++ch) acc[ch] += eA * bf2f(rA[ch]);
  }
  den += __shfl_xor(den, 32);
#pragma unroll
  for (int ch = 0; ch < 8; ++ch) acc[ch] += __shfl_xor(acc[ch], 32);

  if (half == 0) {
    float inv = 1.f / (den + 1e-16f);
    float4 bb0 = *(const float4*)(b1 + c0);
    float4 bb1 = *(const float4*)(b1 + c0 + 4);
    u16x8 o;
    o[0] = f2bf(fmaxf(acc[0] * inv + bb0.x, 0.f));
    o[1] = f2bf(fmaxf(acc[1] * inv + bb0.y, 0.f));
    o[2] = f2bf(fmaxf(acc[2] * inv + bb0.z, 0.f));
    o[3] = f2bf(fmaxf(acc[3] * inv + bb0.w, 0.f));
    o[4] = f2bf(fmaxf(acc[4] * inv + bb1.x, 0.f));
    o[5] = f2bf(fmaxf(acc[5] * inv + bb1.y, 0.f));
    o[6] = f2bf(fmaxf(acc[6] * inv + bb1.z, 0.f));
    o[7] = f2bf(fmaxf(acc[7] * inv + bb1.w, 0.f));
    *(u16x8*)(h1 + (size_t)wid * 256 + c0) = o;
  }
}

// ---------- GCN aggregate: one wave per dst node, 2 edges/load (half-wave split) ----------
__global__ __launch_bounds__(256) void gcn_aggregate(
    const __hip_bfloat16* __restrict__ h2, const int* __restrict__ offs, const int* __restrict__ csr,
    const float* __restrict__ dinv, const float* __restrict__ b2,
    __hip_bfloat16* __restrict__ out2, int n) {
  int wid = (int)(((size_t)blockIdx.x * blockDim.x + threadIdx.x) >> 6);
  if (wid >= n) return;
  int lane = threadIdx.x & 63;
  int half = lane >> 5;
  int l5 = lane & 31;
  int c0 = l5 * 8;
  int base = offs[wid];
  int deg = offs[wid + 1] - base;
  float dn = dinv[wid];
  float acc[8] = {0.f, 0.f, 0.f, 0.f, 0.f, 0.f, 0.f, 0.f};
  int P = deg >> 1;
  int i = 0;
  for (; i + 2 <= P; i += 2) {
    int sA = csr[base + 2 * i + half];
    int sB = csr[base + 2 * i + 2 + half];
    float wA = dinv[sA], wB = dinv[sB];
    u16x8 rA = *(const u16x8*)(h2 + (size_t)sA * 256 + c0);
    u16x8 rB = *(const u16x8*)(h2 + (size_t)sB * 256 + c0);
#pragma unroll
    for (int ch = 0; ch < 8; ++ch) acc[ch] += wA * bf2f(rA[ch]) + wB * bf2f(rB[ch]);
  }
  if (i < P) {
    int sA = csr[base + 2 * i + half];
    float wA = dinv[sA];
    u16x8 rA = *(const u16x8*)(h2 + (size_t)sA * 256 + c0);
#pragma unroll
    for (int ch = 0; ch < 8; ++ch) acc[ch] += wA * bf2f(rA[ch]);
  }
  if ((deg & 1) && half == 0) {
    int sA = csr[base + deg - 1];
    float wA = dinv[sA];
    u16x8 rA = *(const u16x8*)(h2 + (size_t)sA * 256 + c0);
#pragma unroll
    for (int ch = 0; ch < 8; ++ch) acc[ch] += wA * bf2f(rA[ch]);
  }
#pragma unroll
  for (int ch = 0; ch < 8; ++ch) acc[ch] += __shfl_xor(acc[ch], 32);

  if (half == 0) {
    float4 bb0 = *(const float4*)(b2 + c0);
    float4 bb1 = *(const float4*)(b2 + c0 + 4);
    u16x8 o;
    o[0] = f2bf(acc[0] * dn + bb0.x);
    o[1] = f2bf(acc[1] * dn + bb0.y);
    o[2] = f2bf(acc[2] * dn + bb0.z);
    o[3] = f2bf(acc[3] * dn + bb0.w);
    o[4] = f2bf(acc[4] * dn + bb1.x);
    o[5] = f2bf(acc[5] * dn + bb1.y);
    o[6] = f2bf(acc[6] * dn + bb1.z);
    o[7] = f2bf(acc[7] * dn + bb1.w);
    *(u16x8*)(out2 + (size_t)wid * 256 + c0) = o;
  }
}

// ---------- mean pool, stage 1: per-block partial sums with boundary flush ----------
__global__ __launch_bounds__(256) void pool_partial(
    const __hip_bfloat16* __restrict__ out2, const int* __restrict__ batch,
    float* __restrict__ accum, int n) {
  int t = threadIdx.x;
  int start = blockIdx.x * 256;
  if (start >= n) return;
  int end = start + 256; if (end > n) end = n;
  const unsigned short* o16 = (const unsigned short*)out2;
  int curg = batch[start];
  float acc = 0.f;
  for (int i = start; i < end; ++i) {
    int g = batch[i];
    if (g != curg) {
      atomicAdd(&accum[curg * 256 + t], acc);
      acc = 0.f; curg = g;
    }
    acc += bf2f(o16[(size_t)i * 256 + t]);
  }
  atomicAdd(&accum[curg * 256 + t], acc);
}

// ---------- mean pool, stage 2: divide by group count ----------
__global__ __launch_bounds__(256) void pool_finalize(
    const float* __restrict__ accum, const int* __restrict__ batch,
    float* __restrict__ out, int n) {
  __shared__ int sb[2];
  int g = blockIdx.x;
  int t = threadIdx.x;
  if (t < 2) {
    int target = g + t;
    int lo = 0, hi = n;
    while (lo < hi) {
      int mid = (lo + hi) >> 1;
      if (batch[mid] < target) lo = mid + 1; else hi = mid;
    }
    sb[t] = lo;
  }
  __syncthreads();
  int cnt = sb[1] - sb[0];
  out[g * 256 + t] = accum[g * 256 + t] / fmaxf((float)cnt, 1.0f);
}

extern "C" void kernel_launch(void* const* d_in, const int* in_sizes, int n_in,
                              void* d_out, int out_size, void* d_ws, size_t ws_size,
                              hipStream_t stream) {
  const float* x = (const float*)d_in[0];
  const int* ei = (const int*)d_in[1];
  const int* batch = (const int*)d_in[2];
  const float* W1 = (const float*)d_in[3];
  const float* att_s = (const float*)d_in[4];
  const float* att_d = (const float*)d_in[5];
  const float* b1 = (const float*)d_in[6];
  const float* W2 = (const float*)d_in[7];
  const float* b2 = (const float*)d_in[8];
  float* out = (float*)d_out;

  const int n = N_NODES;
  const int e = in_sizes[1] / 2;
  const int* esrc = ei;
  const int* edst = ei + e;

  char* p = (char*)d_ws;
  size_t off_ = 0;
  auto alloc = [&](size_t b) -> void* {
    void* r = p + off_;
    off_ = (off_ + b + 255) & ~(size_t)255;
    return r;
  };
  __hip_bfloat16* hb = (__hip_bfloat16*)alloc((size_t)n * 256 * 2);   // 25.6 MB
  __hip_bfloat16* h1b = (__hip_bfloat16*)alloc((size_t)n * 256 * 2);  // 25.6 MB
  __hip_bfloat16* h2b = (__hip_bfloat16*)alloc((size_t)n * 256 * 2);  // 25.6 MB
  __hip_bfloat16* out2 = (__hip_bfloat16*)alloc((size_t)n * 256 * 2); // 25.6 MB
  float* asrc = (float*)alloc((size_t)n * 4 * 4);
  float* adst = (float*)alloc((size_t)n * 4 * 4);
  int* cnt = (int*)alloc((size_t)n * 4);
  int* offs = (int*)alloc((size_t)(n + 1) * 4);
  int* cur = (int*)alloc((size_t)n * 4);
  int* csr = (int*)alloc((size_t)(e + n) * 4);
  float* dinv = (float*)alloc((size_t)n * 4);
  __hip_bfloat16* W1t = (__hip_bfloat16*)alloc(512 * 256 * 2);
  __hip_bfloat16* W2t = (__hip_bfloat16*)alloc(256 * 256 * 2);
  float* accum = (float*)alloc((size_t)N_GROUPS * 256 * 4);
  unsigned* gkey = (unsigned*)alloc(8 * 4);

  // weight transposes + zeroing
  cvt_transpose<<<(512 * 256 + 255) / 256, 256, 0, stream>>>(W1, W1t, 512, 256);
  cvt_transpose<<<(256 * 256 + 255) / 256, 256, 0, stream>>>(W2, W2t, 256, 256);
  hipMemsetAsync(cnt, 0, (size_t)n * 4, stream);
  hipMemsetAsync(accum, 0, (size_t)N_GROUPS * 256 * 4, stream);
  hipMemsetAsync(gkey, 0, 8 * 4, stream);

  // GEMM1: h = x @ W1   [n,512]x[512,256] -> bf16 (f32 A staged+converted in-kernel)
  dim3 g1((n + 127) / 128, 2);
  gemm_bt<true, true><<<g1, 256, 0, stream>>>(x, W1t, hb, n, 256, 512);

  // attention logits
  att_kernel<<<(n + 3) / 4, 256, 0, stream>>>(hb, att_s, att_d, asrc, adst, n);

  // CSR by dst (with self loops)
  count_deg<<<(e + n + 255) / 256, 256, 0, stream>>>(edst, cnt, e, n);
  scan_kernel<<<1, 1024, 0, stream>>>(cnt, offs, cur, n);
  scatter_edges<<<(e + n + 255) / 256, 256, 0, stream>>>(esrc, edst, cur, csr, e, n);
  compute_dinv<<<(n + 255) / 256, 256, 0, stream>>>(cnt, dinv, n);

  // per-head global alpha upper bound
  att_max<<<128, 256, 0, stream>>>(asrc, adst, gkey, n);

  // GAT aggregate + bias + relu -> bf16 h1
  gat_aggregate<<<(n + 3) / 4, 256, 0, stream>>>(hb, asrc, adst, offs, csr, b1, gkey, h1b, n);

  // GEMM2: h2 = h1 @ W2  [n,256]x[256,256] -> bf16
  gemm_bt<false, true><<<g1, 256, 0, stream>>>(h1b, W2t, h2b, n, 256, 256);

  // GCN aggregate -> bf16 out2
  gcn_aggregate<<<(n + 3) / 4, 256, 0, stream>>>(h2b, offs, csr, dinv, b2, out2, n);

  // mean pool (two-stage)
  pool_partial<<<(n + 255) / 256, 256, 0, stream>>>(out2, batch, accum, n);
  pool_finalize<<<N_GROUPS, 256, 0, stream>>>(accum, batch, out, n);
}

// Round 5
// 578.337 us; speedup vs baseline: 1.6261x; 1.1769x over previous
//
#include <hip/hip_runtime.h>
#include <hip/hip_bf16.h>

#define N_NODES 50000
#define N_GROUPS 50

typedef unsigned short u16x8 __attribute__((ext_vector_type(8)));
typedef unsigned short u16x4 __attribute__((ext_vector_type(4)));
typedef __bf16 bf16x8 __attribute__((ext_vector_type(8)));
typedef float f32x4 __attribute__((ext_vector_type(4)));

__device__ __forceinline__ float bf2f(unsigned short u) {
  union { unsigned int i; float f; } v; v.i = ((unsigned int)u) << 16; return v.f;
}
__device__ __forceinline__ unsigned short f2bf(float f) {
  __hip_bfloat16 b = __float2bfloat16(f);
  return *(unsigned short*)&b;
}
// order-preserving float<->uint keys for atomicMax
__device__ __forceinline__ unsigned fkey(float f) {
  unsigned b = __float_as_uint(f);
  return (b & 0x80000000u) ? ~b : (b | 0x80000000u);
}
__device__ __forceinline__ float keyf(unsigned k) {
  unsigned b = (k & 0x80000000u) ? (k & 0x7fffffffu) : ~k;
  return __uint_as_float(b);
}

// out[c][r] = in[r][c]  (store transposed, bf16)
__global__ void cvt_transpose(const float* __restrict__ in, __hip_bfloat16* __restrict__ out, int R, int C) {
  int i = blockIdx.x * blockDim.x + threadIdx.x;
  if (i < R * C) {
    int r = i / C, c = i % C;
    out[(size_t)c * R + r] = __float2bfloat16(in[i]);
  }
}

// ---------- CSR build ----------
__global__ void count_deg(const int* __restrict__ dst, int* __restrict__ cnt, int e, int n) {
  int i = blockIdx.x * blockDim.x + threadIdx.x;
  if (i < e + n) {
    int d = (i < e) ? dst[i] : (i - e);   // self loops appended
    atomicAdd(&cnt[d], 1);
  }
}

// ---------- hierarchical scan: stage 1 — per-block (256-elem) sums ----------
__global__ __launch_bounds__(256) void scan_part(
    const int* __restrict__ cnt, int* __restrict__ part, int n) {
  int i = blockIdx.x * 256 + threadIdx.x;
  int v = (i < n) ? cnt[i] : 0;
#pragma unroll
  for (int o = 1; o < 64; o <<= 1) v += __shfl_xor(v, o);
  __shared__ int ws[4];
  if ((threadIdx.x & 63) == 0) ws[threadIdx.x >> 6] = v;
  __syncthreads();
  if (threadIdx.x == 0) part[blockIdx.x] = ws[0] + ws[1] + ws[2] + ws[3];
}

// ---------- stage 2: exclusive scan of block partials (nb <= 256), 1 block ----------
__global__ __launch_bounds__(256) void scan_mid(
    int* __restrict__ part, int* __restrict__ offs, int nb, int n) {
  __shared__ int sh[256];
  int t = threadIdx.x;
  int v = (t < nb) ? part[t] : 0;
  sh[t] = v;
  __syncthreads();
  for (int d = 1; d < 256; d <<= 1) {
    int u = (t >= d) ? sh[t - d] : 0;
    __syncthreads();
    sh[t] += u;
    __syncthreads();
  }
  if (t < nb) part[t] = sh[t] - v;          // exclusive base per block
  if (t == nb - 1) offs[n] = sh[t];         // grand total
}

// ---------- stage 3: per-block exclusive scan + base; fuses dinv ----------
__global__ __launch_bounds__(256) void scan_final(
    const int* __restrict__ cnt, const int* __restrict__ part,
    int* __restrict__ offs, int* __restrict__ cur, float* __restrict__ dinv, int n) {
  __shared__ int sh[256];
  int t = threadIdx.x;
  int i = blockIdx.x * 256 + t;
  int v = (i < n) ? cnt[i] : 0;
  sh[t] = v;
  __syncthreads();
  for (int d = 1; d < 256; d <<= 1) {
    int u = (t >= d) ? sh[t - d] : 0;
    __syncthreads();
    sh[t] += u;
    __syncthreads();
  }
  if (i < n) {
    int excl = part[blockIdx.x] + sh[t] - v;
    offs[i] = excl;
    cur[i] = excl;
    int c = v < 1 ? 1 : v;
    dinv[i] = 1.0f / sqrtf((float)c);
  }
}

__global__ void scatter_edges(const int* __restrict__ src, const int* __restrict__ dst,
                              int* __restrict__ cur, int* __restrict__ csr, int e, int n) {
  int i = blockIdx.x * blockDim.x + threadIdx.x;
  if (i < e + n) {
    int s, d;
    if (i < e) { s = src[i]; d = dst[i]; } else { s = i - e; d = i - e; }
    int pos = atomicAdd(&cur[d], 1);
    csr[pos] = s;
  }
}

// ---------- bf16 MFMA GEMM: C[M][Nc] = A[M][K] * Bt[Nc][K]^T ----------
template <bool AF32, bool OUTBF>
__global__ __launch_bounds__(256) void gemm_bt(
    const void* __restrict__ Av, const __hip_bfloat16* __restrict__ Bt,
    void* __restrict__ Cv, int M, int Nc, int K) {
  __shared__ __hip_bfloat16 Ash[128][40];
  __shared__ __hip_bfloat16 Bsh[128][40];
  const int tid = threadIdx.x;
  const int lane = tid & 63;
  const int w = tid >> 6;
  const int wr = (w >> 1) * 64, wc = (w & 1) * 64;
  const int row0 = blockIdx.x * 128, col0 = blockIdx.y * 128;
  const int sr = tid >> 2;
  const int sc = (tid & 3) * 8;

  f32x4 zero4 = {0.f, 0.f, 0.f, 0.f};
  f32x4 acc[4][4];
#pragma unroll
  for (int i = 0; i < 4; i++)
#pragma unroll
    for (int j = 0; j < 4; j++) acc[i][j] = zero4;

  u16x8 z8 = {0, 0, 0, 0, 0, 0, 0, 0};

  auto loadA = [&](int r, int k) -> u16x8 {
    int rr = row0 + r;
    if (rr >= M) return z8;
    if constexpr (AF32) {
      const float* ap = (const float*)Av + (size_t)rr * K + k + sc;
      float4 f0 = *(const float4*)ap;
      float4 f1 = *(const float4*)(ap + 4);
      u16x8 o;
      o[0] = f2bf(f0.x); o[1] = f2bf(f0.y); o[2] = f2bf(f0.z); o[3] = f2bf(f0.w);
      o[4] = f2bf(f1.x); o[5] = f2bf(f1.y); o[6] = f2bf(f1.z); o[7] = f2bf(f1.w);
      return o;
    } else {
      return *(const u16x8*)((const __hip_bfloat16*)Av + (size_t)rr * K + k + sc);
    }
  };
  auto loadB = [&](int r, int k) -> u16x8 {
    int rr = col0 + r;
    if (rr < Nc) return *(const u16x8*)(Bt + (size_t)rr * K + k + sc);
    return z8;
  };

  u16x8 ar0 = loadA(sr, 0), ar1 = loadA(sr + 64, 0);
  u16x8 br0 = loadB(sr, 0), br1 = loadB(sr + 64, 0);

  const int lrow = lane & 15;
  const int lk = (lane >> 4) * 8;

  for (int kt = 0; kt < K; kt += 32) {
    __syncthreads();
    *(u16x8*)&Ash[sr][sc] = ar0;
    *(u16x8*)&Ash[sr + 64][sc] = ar1;
    *(u16x8*)&Bsh[sr][sc] = br0;
    *(u16x8*)&Bsh[sr + 64][sc] = br1;
    __syncthreads();
    int kn = kt + 32;
    if (kn < K) {
      ar0 = loadA(sr, kn); ar1 = loadA(sr + 64, kn);
      br0 = loadB(sr, kn); br1 = loadB(sr + 64, kn);
    }
    bf16x8 av[4], bv[4];
#pragma unroll
    for (int i = 0; i < 4; i++) av[i] = *(const bf16x8*)&Ash[wr + i * 16 + lrow][lk];
#pragma unroll
    for (int j = 0; j < 4; j++) bv[j] = *(const bf16x8*)&Bsh[wc + j * 16 + lrow][lk];
#pragma unroll
    for (int i = 0; i < 4; i++)
#pragma unroll
      for (int j = 0; j < 4; j++)
        acc[i][j] = __builtin_amdgcn_mfma_f32_16x16x32_bf16(av[i], bv[j], acc[i][j], 0, 0, 0);
  }

#pragma unroll
  for (int i = 0; i < 4; i++) {
#pragma unroll
    for (int r = 0; r < 4; r++) {
      int rr = row0 + wr + i * 16 + (lane >> 4) * 4 + r;
      if (rr < M) {
#pragma unroll
        for (int j = 0; j < 4; j++) {
          int cc = col0 + wc + j * 16 + (lane & 15);
          if (cc < Nc) {
            if constexpr (OUTBF) {
              ((__hip_bfloat16*)Cv)[(size_t)rr * Nc + cc] = __float2bfloat16(acc[i][j][r]);
            } else {
              ((float*)Cv)[(size_t)rr * Nc + cc] = acc[i][j][r];
            }
          }
        }
      }
    }
  }
}

// ---------- per-node attention logits: a_src[n][h], a_dst[n][h] (h in bf16) ----------
__global__ __launch_bounds__(256) void att_kernel(
    const __hip_bfloat16* __restrict__ h, const float* __restrict__ att_s, const float* __restrict__ att_d,
    float* __restrict__ a_src, float* __restrict__ a_dst, int n) {
  int wid = (int)(((size_t)blockIdx.x * blockDim.x + threadIdx.x) >> 6);
  if (wid >= n) return;
  int lane = threadIdx.x & 63;
  int c0 = lane * 4;
  u16x4 hv = *(const u16x4*)(h + (size_t)wid * 256 + c0);
  float h0 = bf2f(hv[0]), h1_ = bf2f(hv[1]), h2_ = bf2f(hv[2]), h3 = bf2f(hv[3]);
  float4 as = *(const float4*)(att_s + c0);
  float4 ad = *(const float4*)(att_d + c0);
  float ds_ = h0 * as.x + h1_ * as.y + h2_ * as.z + h3 * as.w;
  float dd_ = h0 * ad.x + h1_ * ad.y + h2_ * ad.z + h3 * ad.w;
#pragma unroll
  for (int m = 1; m < 16; m <<= 1) {
    ds_ += __shfl_xor(ds_, m);
    dd_ += __shfl_xor(dd_, m);
  }
  if ((lane & 15) == 0) {
    a_src[wid * 4 + (lane >> 4)] = ds_;
    a_dst[wid * 4 + (lane >> 4)] = dd_;
  }
}

// ---------- global per-head maxes of a_src / a_dst ----------
__global__ __launch_bounds__(256) void att_max(
    const float* __restrict__ asrc, const float* __restrict__ adst,
    unsigned* __restrict__ gkey, int n) {
  float ms0 = -1e30f, ms1 = -1e30f, ms2 = -1e30f, ms3 = -1e30f;
  float md0 = -1e30f, md1 = -1e30f, md2 = -1e30f, md3 = -1e30f;
  for (int i = blockIdx.x * blockDim.x + threadIdx.x; i < n; i += gridDim.x * blockDim.x) {
    float4 s = *(const float4*)(asrc + (size_t)i * 4);
    float4 d = *(const float4*)(adst + (size_t)i * 4);
    ms0 = fmaxf(ms0, s.x); ms1 = fmaxf(ms1, s.y); ms2 = fmaxf(ms2, s.z); ms3 = fmaxf(ms3, s.w);
    md0 = fmaxf(md0, d.x); md1 = fmaxf(md1, d.y); md2 = fmaxf(md2, d.z); md3 = fmaxf(md3, d.w);
  }
#pragma unroll
  for (int o = 32; o; o >>= 1) {
    ms0 = fmaxf(ms0, __shfl_xor(ms0, o)); ms1 = fmaxf(ms1, __shfl_xor(ms1, o));
    ms2 = fmaxf(ms2, __shfl_xor(ms2, o)); ms3 = fmaxf(ms3, __shfl_xor(ms3, o));
    md0 = fmaxf(md0, __shfl_xor(md0, o)); md1 = fmaxf(md1, __shfl_xor(md1, o));
    md2 = fmaxf(md2, __shfl_xor(md2, o)); md3 = fmaxf(md3, __shfl_xor(md3, o));
  }
  if ((threadIdx.x & 63) == 0) {
    atomicMax(&gkey[0], fkey(ms0)); atomicMax(&gkey[1], fkey(ms1));
    atomicMax(&gkey[2], fkey(ms2)); atomicMax(&gkey[3], fkey(ms3));
    atomicMax(&gkey[4], fkey(md0)); atomicMax(&gkey[5], fkey(md1));
    atomicMax(&gkey[6], fkey(md2)); atomicMax(&gkey[7], fkey(md3));
  }
}

// ---------- GAT aggregate: one wave per dst node, 2 edges/load (half-wave split) ----------
__global__ __launch_bounds__(256) void gat_aggregate(
    const __hip_bfloat16* __restrict__ h, const float* __restrict__ a_src, const float* __restrict__ a_dst,
    const int* __restrict__ offs, const int* __restrict__ csr, const float* __restrict__ b1,
    const unsigned* __restrict__ gkey, __hip_bfloat16* __restrict__ h1, int n) {
  int wid = (int)(((size_t)blockIdx.x * blockDim.x + threadIdx.x) >> 6);
  if (wid >= n) return;
  int lane = threadIdx.x & 63;
  int half = lane >> 5;
  int l5 = lane & 31;
  int c0 = l5 * 8;          // 8 channels per lane, 32 lanes cover 256
  int hl = l5 >> 3;         // head = c0/64
  int base = offs[wid];
  int deg = offs[wid + 1] - base;

  float mh = keyf(gkey[hl]) + keyf(gkey[4 + hl]);
  mh = mh > 0.f ? mh : 0.2f * mh;           // lrelu of upper bound >= all alpha
  float adh = a_dst[wid * 4 + hl];

  float den = 0.f;
  float acc[8] = {0.f, 0.f, 0.f, 0.f, 0.f, 0.f, 0.f, 0.f};
  int P = deg >> 1;
  int i = 0;
  for (; i + 2 <= P; i += 2) {
    int sA = csr[base + 2 * i + half];
    int sB = csr[base + 2 * i + 2 + half];
    float aA = a_src[sA * 4 + hl];
    float aB = a_src[sB * 4 + hl];
    u16x8 rA = *(const u16x8*)(h + (size_t)sA * 256 + c0);
    u16x8 rB = *(const u16x8*)(h + (size_t)sB * 256 + c0);
    float vA = aA + adh; vA = vA > 0.f ? vA : 0.2f * vA;
    float vB = aB + adh; vB = vB > 0.f ? vB : 0.2f * vB;
    float eA = __expf(vA - mh);
    float eB = __expf(vB - mh);
    den += eA + eB;
#pragma unroll
    for (int ch = 0; ch < 8; ++ch) acc[ch] += eA * bf2f(rA[ch]) + eB * bf2f(rB[ch]);
  }
  if (i < P) {
    int sA = csr[base + 2 * i + half];
    float aA = a_src[sA * 4 + hl];
    u16x8 rA = *(const u16x8*)(h + (size_t)sA * 256 + c0);
    float vA = aA + adh; vA = vA > 0.f ? vA : 0.2f * vA;
    float eA = __expf(vA - mh);
    den += eA;
#pragma unroll
    for (int ch = 0; ch < 8; ++ch) acc[ch] += eA * bf2f(rA[ch]);
  }
  if ((deg & 1) && half == 0) {
    int sA = csr[base + deg - 1];
    float aA = a_src[sA * 4 + hl];
    u16x8 rA = *(const u16x8*)(h + (size_t)sA * 256 + c0);
    float vA = aA + adh; vA = vA > 0.f ? vA : 0.2f * vA;
    float eA = __expf(vA - mh);
    den += eA;
#pragma unroll
    for (int ch = 0; ch < 8; ++ch) acc[ch] += eA * bf2f(rA[ch]);
  }
  den += __shfl_xor(den, 32);
#pragma unroll
  for (int ch = 0; ch < 8; ++ch) acc[ch] += __shfl_xor(acc[ch], 32);

  if (half == 0) {
    float inv = 1.f / (den + 1e-16f);
    float4 bb0 = *(const float4*)(b1 + c0);
    float4 bb1 = *(const float4*)(b1 + c0 + 4);
    u16x8 o;
    o[0] = f2bf(fmaxf(acc[0] * inv + bb0.x, 0.f));
    o[1] = f2bf(fmaxf(acc[1] * inv + bb0.y, 0.f));
    o[2] = f2bf(fmaxf(acc[2] * inv + bb0.z, 0.f));
    o[3] = f2bf(fmaxf(acc[3] * inv + bb0.w, 0.f));
    o[4] = f2bf(fmaxf(acc[4] * inv + bb1.x, 0.f));
    o[5] = f2bf(fmaxf(acc[5] * inv + bb1.y, 0.f));
    o[6] = f2bf(fmaxf(acc[6] * inv + bb1.z, 0.f));
    o[7] = f2bf(fmaxf(acc[7] * inv + bb1.w, 0.f));
    *(u16x8*)(h1 + (size_t)wid * 256 + c0) = o;
  }
}

// ---------- GCN aggregate: one wave per dst node, 2 edges/load (half-wave split) ----------
__global__ __launch_bounds__(256) void gcn_aggregate(
    const __hip_bfloat16* __restrict__ h2, const int* __restrict__ offs, const int* __restrict__ csr,
    const float* __restrict__ dinv, const float* __restrict__ b2,
    __hip_bfloat16* __restrict__ out2, int n) {
  int wid = (int)(((size_t)blockIdx.x * blockDim.x + threadIdx.x) >> 6);
  if (wid >= n) return;
  int lane = threadIdx.x & 63;
  int half = lane >> 5;
  int l5 = lane & 31;
  int c0 = l5 * 8;
  int base = offs[wid];
  int deg = offs[wid + 1] - base;
  float dn = dinv[wid];
  float acc[8] = {0.f, 0.f, 0.f, 0.f, 0.f, 0.f, 0.f, 0.f};
  int P = deg >> 1;
  int i = 0;
  for (; i + 2 <= P; i += 2) {
    int sA = csr[base + 2 * i + half];
    int sB = csr[base + 2 * i + 2 + half];
    float wA = dinv[sA], wB = dinv[sB];
    u16x8 rA = *(const u16x8*)(h2 + (size_t)sA * 256 + c0);
    u16x8 rB = *(const u16x8*)(h2 + (size_t)sB * 256 + c0);
#pragma unroll
    for (int ch = 0; ch < 8; ++ch) acc[ch] += wA * bf2f(rA[ch]) + wB * bf2f(rB[ch]);
  }
  if (i < P) {
    int sA = csr[base + 2 * i + half];
    float wA = dinv[sA];
    u16x8 rA = *(const u16x8*)(h2 + (size_t)sA * 256 + c0);
#pragma unroll
    for (int ch = 0; ch < 8; ++ch) acc[ch] += wA * bf2f(rA[ch]);
  }
  if ((deg & 1) && half == 0) {
    int sA = csr[base + deg - 1];
    float wA = dinv[sA];
    u16x8 rA = *(const u16x8*)(h2 + (size_t)sA * 256 + c0);
#pragma unroll
    for (int ch = 0; ch < 8; ++ch) acc[ch] += wA * bf2f(rA[ch]);
  }
#pragma unroll
  for (int ch = 0; ch < 8; ++ch) acc[ch] += __shfl_xor(acc[ch], 32);

  if (half == 0) {
    float4 bb0 = *(const float4*)(b2 + c0);
    float4 bb1 = *(const float4*)(b2 + c0 + 4);
    u16x8 o;
    o[0] = f2bf(acc[0] * dn + bb0.x);
    o[1] = f2bf(acc[1] * dn + bb0.y);
    o[2] = f2bf(acc[2] * dn + bb0.z);
    o[3] = f2bf(acc[3] * dn + bb0.w);
    o[4] = f2bf(acc[4] * dn + bb1.x);
    o[5] = f2bf(acc[5] * dn + bb1.y);
    o[6] = f2bf(acc[6] * dn + bb1.z);
    o[7] = f2bf(acc[7] * dn + bb1.w);
    *(u16x8*)(out2 + (size_t)wid * 256 + c0) = o;
  }
}

// ---------- mean pool, stage 1: per-block partial sums with boundary flush ----------
__global__ __launch_bounds__(256) void pool_partial(
    const __hip_bfloat16* __restrict__ out2, const int* __restrict__ batch,
    float* __restrict__ accum, int n) {
  int t = threadIdx.x;
  int start = blockIdx.x * 256;
  if (start >= n) return;
  int end = start + 256; if (end > n) end = n;
  const unsigned short* o16 = (const unsigned short*)out2;
  int curg = batch[start];
  float acc = 0.f;
  for (int i = start; i < end; ++i) {
    int g = batch[i];
    if (g != curg) {
      atomicAdd(&accum[curg * 256 + t], acc);
      acc = 0.f; curg = g;
    }
    acc += bf2f(o16[(size_t)i * 256 + t]);
  }
  atomicAdd(&accum[curg * 256 + t], acc);
}

// ---------- mean pool, stage 2: divide by group count ----------
__global__ __launch_bounds__(256) void pool_finalize(
    const float* __restrict__ accum, const int* __restrict__ batch,
    float* __restrict__ out, int n) {
  __shared__ int sb[2];
  int g = blockIdx.x;
  int t = threadIdx.x;
  if (t < 2) {
    int target = g + t;
    int lo = 0, hi = n;
    while (lo < hi) {
      int mid = (lo + hi) >> 1;
      if (batch[mid] < target) lo = mid + 1; else hi = mid;
    }
    sb[t] = lo;
  }
  __syncthreads();
  int cnt = sb[1] - sb[0];
  out[g * 256 + t] = accum[g * 256 + t] / fmaxf((float)cnt, 1.0f);
}

extern "C" void kernel_launch(void* const* d_in, const int* in_sizes, int n_in,
                              void* d_out, int out_size, void* d_ws, size_t ws_size,
                              hipStream_t stream) {
  const float* x = (const float*)d_in[0];
  const int* ei = (const int*)d_in[1];
  const int* batch = (const int*)d_in[2];
  const float* W1 = (const float*)d_in[3];
  const float* att_s = (const float*)d_in[4];
  const float* att_d = (const float*)d_in[5];
  const float* b1 = (const float*)d_in[6];
  const float* W2 = (const float*)d_in[7];
  const float* b2 = (const float*)d_in[8];
  float* out = (float*)d_out;

  const int n = N_NODES;
  const int e = in_sizes[1] / 2;
  const int* esrc = ei;
  const int* edst = ei + e;
  const int nb = (n + 255) / 256;   // 196 scan blocks

  char* p = (char*)d_ws;
  size_t off_ = 0;
  auto alloc = [&](size_t b) -> void* {
    void* r = p + off_;
    off_ = (off_ + b + 255) & ~(size_t)255;
    return r;
  };
  __hip_bfloat16* hb = (__hip_bfloat16*)alloc((size_t)n * 256 * 2);   // 25.6 MB
  __hip_bfloat16* h1b = (__hip_bfloat16*)alloc((size_t)n * 256 * 2);  // 25.6 MB
  __hip_bfloat16* h2b = (__hip_bfloat16*)alloc((size_t)n * 256 * 2);  // 25.6 MB
  __hip_bfloat16* out2 = (__hip_bfloat16*)alloc((size_t)n * 256 * 2); // 25.6 MB
  float* asrc = (float*)alloc((size_t)n * 4 * 4);
  float* adst = (float*)alloc((size_t)n * 4 * 4);
  int* cnt = (int*)alloc((size_t)n * 4);
  int* offs = (int*)alloc((size_t)(n + 1) * 4);
  int* cur = (int*)alloc((size_t)n * 4);
  int* csr = (int*)alloc((size_t)(e + n) * 4);
  float* dinv = (float*)alloc((size_t)n * 4);
  int* part = (int*)alloc((size_t)nb * 4);
  __hip_bfloat16* W1t = (__hip_bfloat16*)alloc(512 * 256 * 2);
  __hip_bfloat16* W2t = (__hip_bfloat16*)alloc(256 * 256 * 2);
  float* accum = (float*)alloc((size_t)N_GROUPS * 256 * 4);
  unsigned* gkey = (unsigned*)alloc(8 * 4);

  // weight transposes + zeroing
  cvt_transpose<<<(512 * 256 + 255) / 256, 256, 0, stream>>>(W1, W1t, 512, 256);
  cvt_transpose<<<(256 * 256 + 255) / 256, 256, 0, stream>>>(W2, W2t, 256, 256);
  hipMemsetAsync(cnt, 0, (size_t)n * 4, stream);
  hipMemsetAsync(accum, 0, (size_t)N_GROUPS * 256 * 4, stream);
  hipMemsetAsync(gkey, 0, 8 * 4, stream);

  // GEMM1: h = x @ W1   [n,512]x[512,256] -> bf16 (f32 A staged+converted in-kernel)
  dim3 g1((n + 127) / 128, 2);
  gemm_bt<true, true><<<g1, 256, 0, stream>>>(x, W1t, hb, n, 256, 512);

  // attention logits
  att_kernel<<<(n + 3) / 4, 256, 0, stream>>>(hb, att_s, att_d, asrc, adst, n);

  // CSR by dst (with self loops) — hierarchical scan, dinv fused in stage 3
  count_deg<<<(e + n + 255) / 256, 256, 0, stream>>>(edst, cnt, e, n);
  scan_part<<<nb, 256, 0, stream>>>(cnt, part, n);
  scan_mid<<<1, 256, 0, stream>>>(part, offs, nb, n);
  scan_final<<<nb, 256, 0, stream>>>(cnt, part, offs, cur, dinv, n);
  scatter_edges<<<(e + n + 255) / 256, 256, 0, stream>>>(esrc, edst, cur, csr, e, n);

  // per-head global alpha upper bound
  att_max<<<128, 256, 0, stream>>>(asrc, adst, gkey, n);

  // GAT aggregate + bias + relu -> bf16 h1
  gat_aggregate<<<(n + 3) / 4, 256, 0, stream>>>(hb, asrc, adst, offs, csr, b1, gkey, h1b, n);

  // GEMM2: h2 = h1 @ W2  [n,256]x[256,256] -> bf16
  gemm_bt<false, true><<<g1, 256, 0, stream>>>(h1b, W2t, h2b, n, 256, 256);

  // GCN aggregate -> bf16 out2
  gcn_aggregate<<<(n + 3) / 4, 256, 0, stream>>>(h2b, offs, csr, dinv, b2, out2, n);

  // mean pool (two-stage)
  pool_partial<<<(n + 255) / 256, 256, 0, stream>>>(out2, batch, accum, n);
  pool_finalize<<<N_GROUPS, 256, 0, stream>>>(accum, batch, out, n);
}

// Round 6
// 522.302 us; speedup vs baseline: 1.8005x; 1.1073x over previous
//
#include <hip/hip_runtime.h>
#include <hip/hip_bf16.h>

#define N_NODES 50000
#define N_GROUPS 50

typedef unsigned short u16x8 __attribute__((ext_vector_type(8)));
typedef unsigned short u16x4 __attribute__((ext_vector_type(4)));
typedef __bf16 bf16x8 __attribute__((ext_vector_type(8)));
typedef float f32x4 __attribute__((ext_vector_type(4)));

__device__ __forceinline__ float bf2f(unsigned short u) {
  union { unsigned int i; float f; } v; v.i = ((unsigned int)u) << 16; return v.f;
}
__device__ __forceinline__ unsigned short f2bf(float f) {
  __hip_bfloat16 b = __float2bfloat16(f);
  return *(unsigned short*)&b;
}
// order-preserving float<->uint keys for atomicMax
__device__ __forceinline__ unsigned fkey(float f) {
  unsigned b = __float_as_uint(f);
  return (b & 0x80000000u) ? ~b : (b | 0x80000000u);
}
__device__ __forceinline__ float keyf(unsigned k) {
  unsigned b = (k & 0x80000000u) ? (k & 0x7fffffffu) : ~k;
  return __uint_as_float(b);
}

// out[c][r] = in[r][c]  (store transposed, bf16)
__global__ void cvt_transpose(const float* __restrict__ in, __hip_bfloat16* __restrict__ out, int R, int C) {
  int i = blockIdx.x * blockDim.x + threadIdx.x;
  if (i < R * C) {
    int r = i / C, c = i % C;
    out[(size_t)c * R + r] = __float2bfloat16(in[i]);
  }
}

// ---------- CSR build ----------
__global__ void count_deg(const int* __restrict__ dst, int* __restrict__ cnt, int e, int n) {
  int i = blockIdx.x * blockDim.x + threadIdx.x;
  if (i < e + n) {
    int d = (i < e) ? dst[i] : (i - e);   // self loops appended
    atomicAdd(&cnt[d], 1);
  }
}

// ---------- hierarchical scan: stage 1 — per-block (256-elem) sums ----------
__global__ __launch_bounds__(256) void scan_part(
    const int* __restrict__ cnt, int* __restrict__ part, int n) {
  int i = blockIdx.x * 256 + threadIdx.x;
  int v = (i < n) ? cnt[i] : 0;
#pragma unroll
  for (int o = 1; o < 64; o <<= 1) v += __shfl_xor(v, o);
  __shared__ int ws[4];
  if ((threadIdx.x & 63) == 0) ws[threadIdx.x >> 6] = v;
  __syncthreads();
  if (threadIdx.x == 0) part[blockIdx.x] = ws[0] + ws[1] + ws[2] + ws[3];
}

// ---------- stage 2: exclusive scan of block partials (nb <= 256), 1 block ----------
__global__ __launch_bounds__(256) void scan_mid(
    int* __restrict__ part, int* __restrict__ offs, int nb, int n) {
  __shared__ int sh[256];
  int t = threadIdx.x;
  int v = (t < nb) ? part[t] : 0;
  sh[t] = v;
  __syncthreads();
  for (int d = 1; d < 256; d <<= 1) {
    int u = (t >= d) ? sh[t - d] : 0;
    __syncthreads();
    sh[t] += u;
    __syncthreads();
  }
  if (t < nb) part[t] = sh[t] - v;          // exclusive base per block
  if (t == nb - 1) offs[n] = sh[t];         // grand total
}

// ---------- stage 3: per-block exclusive scan + base; fuses dinv ----------
__global__ __launch_bounds__(256) void scan_final(
    const int* __restrict__ cnt, const int* __restrict__ part,
    int* __restrict__ offs, int* __restrict__ cur, float* __restrict__ dinv, int n) {
  __shared__ int sh[256];
  int t = threadIdx.x;
  int i = blockIdx.x * 256 + t;
  int v = (i < n) ? cnt[i] : 0;
  sh[t] = v;
  __syncthreads();
  for (int d = 1; d < 256; d <<= 1) {
    int u = (t >= d) ? sh[t - d] : 0;
    __syncthreads();
    sh[t] += u;
    __syncthreads();
  }
  if (i < n) {
    int excl = part[blockIdx.x] + sh[t] - v;
    offs[i] = excl;
    cur[i] = excl;
    int c = v < 1 ? 1 : v;
    dinv[i] = 1.0f / sqrtf((float)c);
  }
}

__global__ void scatter_edges(const int* __restrict__ src, const int* __restrict__ dst,
                              int* __restrict__ cur, int* __restrict__ csr, int e, int n) {
  int i = blockIdx.x * blockDim.x + threadIdx.x;
  if (i < e + n) {
    int s, d;
    if (i < e) { s = src[i]; d = dst[i]; } else { s = i - e; d = i - e; }
    int pos = atomicAdd(&cur[d], 1);
    csr[pos] = s;
  }
}

// ---------- bf16 MFMA GEMM: C[M][Nc] = A[M][K] * Bt[Nc][K]^T ----------
template <bool AF32, bool OUTBF>
__global__ __launch_bounds__(256) void gemm_bt(
    const void* __restrict__ Av, const __hip_bfloat16* __restrict__ Bt,
    void* __restrict__ Cv, int M, int Nc, int K) {
  __shared__ __hip_bfloat16 Ash[128][40];
  __shared__ __hip_bfloat16 Bsh[128][40];
  const int tid = threadIdx.x;
  const int lane = tid & 63;
  const int w = tid >> 6;
  const int wr = (w >> 1) * 64, wc = (w & 1) * 64;
  const int row0 = blockIdx.x * 128, col0 = blockIdx.y * 128;
  const int sr = tid >> 2;
  const int sc = (tid & 3) * 8;

  f32x4 zero4 = {0.f, 0.f, 0.f, 0.f};
  f32x4 acc[4][4];
#pragma unroll
  for (int i = 0; i < 4; i++)
#pragma unroll
    for (int j = 0; j < 4; j++) acc[i][j] = zero4;

  u16x8 z8 = {0, 0, 0, 0, 0, 0, 0, 0};

  auto loadA = [&](int r, int k) -> u16x8 {
    int rr = row0 + r;
    if (rr >= M) return z8;
    if constexpr (AF32) {
      const float* ap = (const float*)Av + (size_t)rr * K + k + sc;
      float4 f0 = *(const float4*)ap;
      float4 f1 = *(const float4*)(ap + 4);
      u16x8 o;
      o[0] = f2bf(f0.x); o[1] = f2bf(f0.y); o[2] = f2bf(f0.z); o[3] = f2bf(f0.w);
      o[4] = f2bf(f1.x); o[5] = f2bf(f1.y); o[6] = f2bf(f1.z); o[7] = f2bf(f1.w);
      return o;
    } else {
      return *(const u16x8*)((const __hip_bfloat16*)Av + (size_t)rr * K + k + sc);
    }
  };
  auto loadB = [&](int r, int k) -> u16x8 {
    int rr = col0 + r;
    if (rr < Nc) return *(const u16x8*)(Bt + (size_t)rr * K + k + sc);
    return z8;
  };

  u16x8 ar0 = loadA(sr, 0), ar1 = loadA(sr + 64, 0);
  u16x8 br0 = loadB(sr, 0), br1 = loadB(sr + 64, 0);

  const int lrow = lane & 15;
  const int lk = (lane >> 4) * 8;

  for (int kt = 0; kt < K; kt += 32) {
    __syncthreads();
    *(u16x8*)&Ash[sr][sc] = ar0;
    *(u16x8*)&Ash[sr + 64][sc] = ar1;
    *(u16x8*)&Bsh[sr][sc] = br0;
    *(u16x8*)&Bsh[sr + 64][sc] = br1;
    __syncthreads();
    int kn = kt + 32;
    if (kn < K) {
      ar0 = loadA(sr, kn); ar1 = loadA(sr + 64, kn);
      br0 = loadB(sr, kn); br1 = loadB(sr + 64, kn);
    }
    bf16x8 av[4], bv[4];
#pragma unroll
    for (int i = 0; i < 4; i++) av[i] = *(const bf16x8*)&Ash[wr + i * 16 + lrow][lk];
#pragma unroll
    for (int j = 0; j < 4; j++) bv[j] = *(const bf16x8*)&Bsh[wc + j * 16 + lrow][lk];
#pragma unroll
    for (int i = 0; i < 4; i++)
#pragma unroll
      for (int j = 0; j < 4; j++)
        acc[i][j] = __builtin_amdgcn_mfma_f32_16x16x32_bf16(av[i], bv[j], acc[i][j], 0, 0, 0);
  }

#pragma unroll
  for (int i = 0; i < 4; i++) {
#pragma unroll
    for (int r = 0; r < 4; r++) {
      int rr = row0 + wr + i * 16 + (lane >> 4) * 4 + r;
      if (rr < M) {
#pragma unroll
        for (int j = 0; j < 4; j++) {
          int cc = col0 + wc + j * 16 + (lane & 15);
          if (cc < Nc) {
            if constexpr (OUTBF) {
              ((__hip_bfloat16*)Cv)[(size_t)rr * Nc + cc] = __float2bfloat16(acc[i][j][r]);
            } else {
              ((float*)Cv)[(size_t)rr * Nc + cc] = acc[i][j][r];
            }
          }
        }
      }
    }
  }
}

// ---------- per-node attention logits: a_src[n][h], a_dst[n][h] (h in bf16) ----------
__global__ __launch_bounds__(256) void att_kernel(
    const __hip_bfloat16* __restrict__ h, const float* __restrict__ att_s, const float* __restrict__ att_d,
    float* __restrict__ a_src, float* __restrict__ a_dst, int n) {
  int wid = (int)(((size_t)blockIdx.x * blockDim.x + threadIdx.x) >> 6);
  if (wid >= n) return;
  int lane = threadIdx.x & 63;
  int c0 = lane * 4;
  u16x4 hv = *(const u16x4*)(h + (size_t)wid * 256 + c0);
  float h0 = bf2f(hv[0]), h1_ = bf2f(hv[1]), h2_ = bf2f(hv[2]), h3 = bf2f(hv[3]);
  float4 as = *(const float4*)(att_s + c0);
  float4 ad = *(const float4*)(att_d + c0);
  float ds_ = h0 * as.x + h1_ * as.y + h2_ * as.z + h3 * as.w;
  float dd_ = h0 * ad.x + h1_ * ad.y + h2_ * ad.z + h3 * ad.w;
#pragma unroll
  for (int m = 1; m < 16; m <<= 1) {
    ds_ += __shfl_xor(ds_, m);
    dd_ += __shfl_xor(dd_, m);
  }
  if ((lane & 15) == 0) {
    a_src[wid * 4 + (lane >> 4)] = ds_;
    a_dst[wid * 4 + (lane >> 4)] = dd_;
  }
}

// ---------- global per-head maxes of a_src / a_dst ----------
__global__ __launch_bounds__(256) void att_max(
    const float* __restrict__ asrc, const float* __restrict__ adst,
    unsigned* __restrict__ gkey, int n) {
  float ms0 = -1e30f, ms1 = -1e30f, ms2 = -1e30f, ms3 = -1e30f;
  float md0 = -1e30f, md1 = -1e30f, md2 = -1e30f, md3 = -1e30f;
  for (int i = blockIdx.x * blockDim.x + threadIdx.x; i < n; i += gridDim.x * blockDim.x) {
    float4 s = *(const float4*)(asrc + (size_t)i * 4);
    float4 d = *(const float4*)(adst + (size_t)i * 4);
    ms0 = fmaxf(ms0, s.x); ms1 = fmaxf(ms1, s.y); ms2 = fmaxf(ms2, s.z); ms3 = fmaxf(ms3, s.w);
    md0 = fmaxf(md0, d.x); md1 = fmaxf(md1, d.y); md2 = fmaxf(md2, d.z); md3 = fmaxf(md3, d.w);
  }
#pragma unroll
  for (int o = 32; o; o >>= 1) {
    ms0 = fmaxf(ms0, __shfl_xor(ms0, o)); ms1 = fmaxf(ms1, __shfl_xor(ms1, o));
    ms2 = fmaxf(ms2, __shfl_xor(ms2, o)); ms3 = fmaxf(ms3, __shfl_xor(ms3, o));
    md0 = fmaxf(md0, __shfl_xor(md0, o)); md1 = fmaxf(md1, __shfl_xor(md1, o));
    md2 = fmaxf(md2, __shfl_xor(md2, o)); md3 = fmaxf(md3, __shfl_xor(md3, o));
  }
  if ((threadIdx.x & 63) == 0) {
    atomicMax(&gkey[0], fkey(ms0)); atomicMax(&gkey[1], fkey(ms1));
    atomicMax(&gkey[2], fkey(ms2)); atomicMax(&gkey[3], fkey(ms3));
    atomicMax(&gkey[4], fkey(md0)); atomicMax(&gkey[5], fkey(md1));
    atomicMax(&gkey[6], fkey(md2)); atomicMax(&gkey[7], fkey(md3));
  }
}

// ---------- GAT aggregate: one wave per dst node, 2 edges/load (half-wave split) ----------
__global__ __launch_bounds__(256) void gat_aggregate(
    const __hip_bfloat16* __restrict__ h, const float* __restrict__ a_src, const float* __restrict__ a_dst,
    const int* __restrict__ offs, const int* __restrict__ csr, const float* __restrict__ b1,
    const unsigned* __restrict__ gkey, __hip_bfloat16* __restrict__ h1, int n) {
  int wid = (int)(((size_t)blockIdx.x * blockDim.x + threadIdx.x) >> 6);
  if (wid >= n) return;
  int lane = threadIdx.x & 63;
  int half = lane >> 5;
  int l5 = lane & 31;
  int c0 = l5 * 8;          // 8 channels per lane, 32 lanes cover 256
  int hl = l5 >> 3;         // head = c0/64
  int base = offs[wid];
  int deg = offs[wid + 1] - base;

  float mh = keyf(gkey[hl]) + keyf(gkey[4 + hl]);
  mh = mh > 0.f ? mh : 0.2f * mh;           // lrelu of upper bound >= all alpha
  float adh = a_dst[wid * 4 + hl];

  float den = 0.f;
  float acc[8] = {0.f, 0.f, 0.f, 0.f, 0.f, 0.f, 0.f, 0.f};
  int P = deg >> 1;
  int i = 0;
  for (; i + 2 <= P; i += 2) {
    int sA = csr[base + 2 * i + half];
    int sB = csr[base + 2 * i + 2 + half];
    float aA = a_src[sA * 4 + hl];
    float aB = a_src[sB * 4 + hl];
    u16x8 rA = *(const u16x8*)(h + (size_t)sA * 256 + c0);
    u16x8 rB = *(const u16x8*)(h + (size_t)sB * 256 + c0);
    float vA = aA + adh; vA = vA > 0.f ? vA : 0.2f * vA;
    float vB = aB + adh; vB = vB > 0.f ? vB : 0.2f * vB;
    float eA = __expf(vA - mh);
    float eB = __expf(vB - mh);
    den += eA + eB;
#pragma unroll
    for (int ch = 0; ch < 8; ++ch) acc[ch] += eA * bf2f(rA[ch]) + eB * bf2f(rB[ch]);
  }
  if (i < P) {
    int sA = csr[base + 2 * i + half];
    float aA = a_src[sA * 4 + hl];
    u16x8 rA = *(const u16x8*)(h + (size_t)sA * 256 + c0);
    float vA = aA + adh; vA = vA > 0.f ? vA : 0.2f * vA;
    float eA = __expf(vA - mh);
    den += eA;
#pragma unroll
    for (int ch = 0; ch < 8; ++ch) acc[ch] += eA * bf2f(rA[ch]);
  }
  if ((deg & 1) && half == 0) {
    int sA = csr[base + deg - 1];
    float aA = a_src[sA * 4 + hl];
    u16x8 rA = *(const u16x8*)(h + (size_t)sA * 256 + c0);
    float vA = aA + adh; vA = vA > 0.f ? vA : 0.2f * vA;
    float eA = __expf(vA - mh);
    den += eA;
#pragma unroll
    for (int ch = 0; ch < 8; ++ch) acc[ch] += eA * bf2f(rA[ch]);
  }
  den += __shfl_xor(den, 32);
#pragma unroll
  for (int ch = 0; ch < 8; ++ch) acc[ch] += __shfl_xor(acc[ch], 32);

  if (half == 0) {
    float inv = 1.f / (den + 1e-16f);
    float4 bb0 = *(const float4*)(b1 + c0);
    float4 bb1 = *(const float4*)(b1 + c0 + 4);
    u16x8 o;
    o[0] = f2bf(fmaxf(acc[0] * inv + bb0.x, 0.f));
    o[1] = f2bf(fmaxf(acc[1] * inv + bb0.y, 0.f));
    o[2] = f2bf(fmaxf(acc[2] * inv + bb0.z, 0.f));
    o[3] = f2bf(fmaxf(acc[3] * inv + bb0.w, 0.f));
    o[4] = f2bf(fmaxf(acc[4] * inv + bb1.x, 0.f));
    o[5] = f2bf(fmaxf(acc[5] * inv + bb1.y, 0.f));
    o[6] = f2bf(fmaxf(acc[6] * inv + bb1.z, 0.f));
    o[7] = f2bf(fmaxf(acc[7] * inv + bb1.w, 0.f));
    *(u16x8*)(h1 + (size_t)wid * 256 + c0) = o;
  }
}

// ---------- GCN aggregate: one wave per dst node, 2 edges/load (half-wave split) ----------
__global__ __launch_bounds__(256) void gcn_aggregate(
    const __hip_bfloat16* __restrict__ h2, const int* __restrict__ offs, const int* __restrict__ csr,
    const float* __restrict__ dinv, const float* __restrict__ b2,
    __hip_bfloat16* __restrict__ out2, int n) {
  int wid = (int)(((size_t)blockIdx.x * blockDim.x + threadIdx.x) >> 6);
  if (wid >= n) return;
  int lane = threadIdx.x & 63;
  int half = lane >> 5;
  int l5 = lane & 31;
  int c0 = l5 * 8;
  int base = offs[wid];
  int deg = offs[wid + 1] - base;
  float dn = dinv[wid];
  float acc[8] = {0.f, 0.f, 0.f, 0.f, 0.f, 0.f, 0.f, 0.f};
  int P = deg >> 1;
  int i = 0;
  for (; i + 2 <= P; i += 2) {
    int sA = csr[base + 2 * i + half];
    int sB = csr[base + 2 * i + 2 + half];
    float wA = dinv[sA], wB = dinv[sB];
    u16x8 rA = *(const u16x8*)(h2 + (size_t)sA * 256 + c0);
    u16x8 rB = *(const u16x8*)(h2 + (size_t)sB * 256 + c0);
#pragma unroll
    for (int ch = 0; ch < 8; ++ch) acc[ch] += wA * bf2f(rA[ch]) + wB * bf2f(rB[ch]);
  }
  if (i < P) {
    int sA = csr[base + 2 * i + half];
    float wA = dinv[sA];
    u16x8 rA = *(const u16x8*)(h2 + (size_t)sA * 256 + c0);
#pragma unroll
    for (int ch = 0; ch < 8; ++ch) acc[ch] += wA * bf2f(rA[ch]);
  }
  if ((deg & 1) && half == 0) {
    int sA = csr[base + deg - 1];
    float wA = dinv[sA];
    u16x8 rA = *(const u16x8*)(h2 + (size_t)sA * 256 + c0);
#pragma unroll
    for (int ch = 0; ch < 8; ++ch) acc[ch] += wA * bf2f(rA[ch]);
  }
#pragma unroll
  for (int ch = 0; ch < 8; ++ch) acc[ch] += __shfl_xor(acc[ch], 32);

  if (half == 0) {
    float4 bb0 = *(const float4*)(b2 + c0);
    float4 bb1 = *(const float4*)(b2 + c0 + 4);
    u16x8 o;
    o[0] = f2bf(acc[0] * dn + bb0.x);
    o[1] = f2bf(acc[1] * dn + bb0.y);
    o[2] = f2bf(acc[2] * dn + bb0.z);
    o[3] = f2bf(acc[3] * dn + bb0.w);
    o[4] = f2bf(acc[4] * dn + bb1.x);
    o[5] = f2bf(acc[5] * dn + bb1.y);
    o[6] = f2bf(acc[6] * dn + bb1.z);
    o[7] = f2bf(acc[7] * dn + bb1.w);
    *(u16x8*)(out2 + (size_t)wid * 256 + c0) = o;
  }
}

// ---------- mean pool, stage 1: 64 rows/block, 4 waves x 16 rows, LDS-combine ----------
__global__ __launch_bounds__(256) void pool_partial(
    const __hip_bfloat16* __restrict__ out2, const int* __restrict__ batch,
    float* __restrict__ accum, int n) {
  __shared__ float lds[3][256];
  int tid = threadIdx.x;
  int w = tid >> 6, lane = tid & 63;
  int base = blockIdx.x * 64;
  if (base >= n) return;
  int last = base + 63; if (last > n - 1) last = n - 1;
  int g0 = batch[base], g1 = batch[last];
  int c0 = lane * 4;
  const unsigned short* o16 = (const unsigned short*)out2;
  int rs = base + w * 16;
  int re = rs + 16; if (re > n) re = n;
  float a0 = 0.f, a1 = 0.f, a2 = 0.f, a3 = 0.f;

  if (g0 == g1) {
    // fast path: whole block is one group; no per-row batch reads
    for (int r = rs; r < re; ++r) {
      u16x4 v = *(const u16x4*)(o16 + (size_t)r * 256 + c0);
      a0 += bf2f(v[0]); a1 += bf2f(v[1]); a2 += bf2f(v[2]); a3 += bf2f(v[3]);
    }
    if (w > 0) {
      lds[w - 1][c0] = a0; lds[w - 1][c0 + 1] = a1;
      lds[w - 1][c0 + 2] = a2; lds[w - 1][c0 + 3] = a3;
    }
    __syncthreads();
    if (w == 0) {
#pragma unroll
      for (int k = 0; k < 3; ++k) {
        a0 += lds[k][c0]; a1 += lds[k][c0 + 1];
        a2 += lds[k][c0 + 2]; a3 += lds[k][c0 + 3];
      }
      float* dst = &accum[(size_t)g0 * 256 + c0];
      atomicAdd(dst, a0); atomicAdd(dst + 1, a1);
      atomicAdd(dst + 2, a2); atomicAdd(dst + 3, a3);
    }
  } else {
    // slow path: group boundary inside block — per-wave exact flushes
    int curg = -1;
    for (int r = rs; r < re; ++r) {
      int g = batch[r];
      if (g != curg) {
        if (curg >= 0) {
          float* dst = &accum[(size_t)curg * 256 + c0];
          atomicAdd(dst, a0); atomicAdd(dst + 1, a1);
          atomicAdd(dst + 2, a2); atomicAdd(dst + 3, a3);
          a0 = a1 = a2 = a3 = 0.f;
        }
        curg = g;
      }
      u16x4 v = *(const u16x4*)(o16 + (size_t)r * 256 + c0);
      a0 += bf2f(v[0]); a1 += bf2f(v[1]); a2 += bf2f(v[2]); a3 += bf2f(v[3]);
    }
    if (curg >= 0) {
      float* dst = &accum[(size_t)curg * 256 + c0];
      atomicAdd(dst, a0); atomicAdd(dst + 1, a1);
      atomicAdd(dst + 2, a2); atomicAdd(dst + 3, a3);
    }
  }
}

// ---------- mean pool, stage 2: divide by group count ----------
__global__ __launch_bounds__(256) void pool_finalize(
    const float* __restrict__ accum, const int* __restrict__ batch,
    float* __restrict__ out, int n) {
  __shared__ int sb[2];
  int g = blockIdx.x;
  int t = threadIdx.x;
  if (t < 2) {
    int target = g + t;
    int lo = 0, hi = n;
    while (lo < hi) {
      int mid = (lo + hi) >> 1;
      if (batch[mid] < target) lo = mid + 1; else hi = mid;
    }
    sb[t] = lo;
  }
  __syncthreads();
  int cnt = sb[1] - sb[0];
  out[g * 256 + t] = accum[g * 256 + t] / fmaxf((float)cnt, 1.0f);
}

extern "C" void kernel_launch(void* const* d_in, const int* in_sizes, int n_in,
                              void* d_out, int out_size, void* d_ws, size_t ws_size,
                              hipStream_t stream) {
  const float* x = (const float*)d_in[0];
  const int* ei = (const int*)d_in[1];
  const int* batch = (const int*)d_in[2];
  const float* W1 = (const float*)d_in[3];
  const float* att_s = (const float*)d_in[4];
  const float* att_d = (const float*)d_in[5];
  const float* b1 = (const float*)d_in[6];
  const float* W2 = (const float*)d_in[7];
  const float* b2 = (const float*)d_in[8];
  float* out = (float*)d_out;

  const int n = N_NODES;
  const int e = in_sizes[1] / 2;
  const int* esrc = ei;
  const int* edst = ei + e;
  const int nb = (n + 255) / 256;   // 196 scan blocks

  char* p = (char*)d_ws;
  size_t off_ = 0;
  auto alloc = [&](size_t b) -> void* {
    void* r = p + off_;
    off_ = (off_ + b + 255) & ~(size_t)255;
    return r;
  };
  __hip_bfloat16* hb = (__hip_bfloat16*)alloc((size_t)n * 256 * 2);   // 25.6 MB
  __hip_bfloat16* h1b = (__hip_bfloat16*)alloc((size_t)n * 256 * 2);  // 25.6 MB
  __hip_bfloat16* h2b = (__hip_bfloat16*)alloc((size_t)n * 256 * 2);  // 25.6 MB
  __hip_bfloat16* out2 = (__hip_bfloat16*)alloc((size_t)n * 256 * 2); // 25.6 MB
  float* asrc = (float*)alloc((size_t)n * 4 * 4);
  float* adst = (float*)alloc((size_t)n * 4 * 4);
  int* cnt = (int*)alloc((size_t)n * 4);
  int* offs = (int*)alloc((size_t)(n + 1) * 4);
  int* cur = (int*)alloc((size_t)n * 4);
  int* csr = (int*)alloc((size_t)(e + n) * 4);
  float* dinv = (float*)alloc((size_t)n * 4);
  int* part = (int*)alloc((size_t)nb * 4);
  __hip_bfloat16* W1t = (__hip_bfloat16*)alloc(512 * 256 * 2);
  __hip_bfloat16* W2t = (__hip_bfloat16*)alloc(256 * 256 * 2);
  float* accum = (float*)alloc((size_t)N_GROUPS * 256 * 4);
  unsigned* gkey = (unsigned*)alloc(8 * 4);

  // weight transposes + zeroing
  cvt_transpose<<<(512 * 256 + 255) / 256, 256, 0, stream>>>(W1, W1t, 512, 256);
  cvt_transpose<<<(256 * 256 + 255) / 256, 256, 0, stream>>>(W2, W2t, 256, 256);
  hipMemsetAsync(cnt, 0, (size_t)n * 4, stream);
  hipMemsetAsync(accum, 0, (size_t)N_GROUPS * 256 * 4, stream);
  hipMemsetAsync(gkey, 0, 8 * 4, stream);

  // GEMM1: h = x @ W1   [n,512]x[512,256] -> bf16 (f32 A staged+converted in-kernel)
  dim3 g1((n + 127) / 128, 2);
  gemm_bt<true, true><<<g1, 256, 0, stream>>>(x, W1t, hb, n, 256, 512);

  // attention logits
  att_kernel<<<(n + 3) / 4, 256, 0, stream>>>(hb, att_s, att_d, asrc, adst, n);

  // CSR by dst (with self loops) — hierarchical scan, dinv fused in stage 3
  count_deg<<<(e + n + 255) / 256, 256, 0, stream>>>(edst, cnt, e, n);
  scan_part<<<nb, 256, 0, stream>>>(cnt, part, n);
  scan_mid<<<1, 256, 0, stream>>>(part, offs, nb, n);
  scan_final<<<nb, 256, 0, stream>>>(cnt, part, offs, cur, dinv, n);
  scatter_edges<<<(e + n + 255) / 256, 256, 0, stream>>>(esrc, edst, cur, csr, e, n);

  // per-head global alpha upper bound
  att_max<<<128, 256, 0, stream>>>(asrc, adst, gkey, n);

  // GAT aggregate + bias + relu -> bf16 h1
  gat_aggregate<<<(n + 3) / 4, 256, 0, stream>>>(hb, asrc, adst, offs, csr, b1, gkey, h1b, n);

  // GEMM2: h2 = h1 @ W2  [n,256]x[256,256] -> bf16
  gemm_bt<false, true><<<g1, 256, 0, stream>>>(h1b, W2t, h2b, n, 256, 256);

  // GCN aggregate -> bf16 out2
  gcn_aggregate<<<(n + 3) / 4, 256, 0, stream>>>(h2b, offs, csr, dinv, b2, out2, n);

  // mean pool (two-stage)
  pool_partial<<<(n + 63) / 64, 256, 0, stream>>>(out2, batch, accum, n);
  pool_finalize<<<N_GROUPS, 256, 0, stream>>>(accum, batch, out, n);
}

// Round 7
// 511.949 us; speedup vs baseline: 1.8369x; 1.0202x over previous
//
#include <hip/hip_runtime.h>
#include <hip/hip_bf16.h>

#define N_NODES 50000
#define N_GROUPS 50

typedef unsigned short u16x8 __attribute__((ext_vector_type(8)));
typedef unsigned short u16x4 __attribute__((ext_vector_type(4)));
typedef __bf16 bf16x8 __attribute__((ext_vector_type(8)));
typedef float f32x4 __attribute__((ext_vector_type(4)));

__device__ __forceinline__ float bf2f(unsigned short u) {
  union { unsigned int i; float f; } v; v.i = ((unsigned int)u) << 16; return v.f;
}
__device__ __forceinline__ unsigned short f2bf(float f) {
  __hip_bfloat16 b = __float2bfloat16(f);
  return *(unsigned short*)&b;
}
// order-preserving float<->uint keys for atomicMax
__device__ __forceinline__ unsigned fkey(float f) {
  unsigned b = __float_as_uint(f);
  return (b & 0x80000000u) ? ~b : (b | 0x80000000u);
}
__device__ __forceinline__ float keyf(unsigned k) {
  unsigned b = (k & 0x80000000u) ? (k & 0x7fffffffu) : ~k;
  return __uint_as_float(b);
}

// out[c][r] = in[r][c]  (store transposed, bf16)
__global__ void cvt_transpose(const float* __restrict__ in, __hip_bfloat16* __restrict__ out, int R, int C) {
  int i = blockIdx.x * blockDim.x + threadIdx.x;
  if (i < R * C) {
    int r = i / C, c = i % C;
    out[(size_t)c * R + r] = __float2bfloat16(in[i]);
  }
}

// ---------- CSR build ----------
__global__ void count_deg(const int* __restrict__ dst, int* __restrict__ cnt, int e, int n) {
  int i = blockIdx.x * blockDim.x + threadIdx.x;
  if (i < e + n) {
    int d = (i < e) ? dst[i] : (i - e);   // self loops appended
    atomicAdd(&cnt[d], 1);
  }
}

// ---------- hierarchical scan: stage 1 — per-block (256-elem) sums ----------
__global__ __launch_bounds__(256) void scan_part(
    const int* __restrict__ cnt, int* __restrict__ part, int n) {
  int i = blockIdx.x * 256 + threadIdx.x;
  int v = (i < n) ? cnt[i] : 0;
#pragma unroll
  for (int o = 1; o < 64; o <<= 1) v += __shfl_xor(v, o);
  __shared__ int ws[4];
  if ((threadIdx.x & 63) == 0) ws[threadIdx.x >> 6] = v;
  __syncthreads();
  if (threadIdx.x == 0) part[blockIdx.x] = ws[0] + ws[1] + ws[2] + ws[3];
}

// ---------- stage 2: exclusive scan of block partials (nb <= 256), 1 block ----------
__global__ __launch_bounds__(256) void scan_mid(
    int* __restrict__ part, int* __restrict__ offs, int nb, int n) {
  __shared__ int sh[256];
  int t = threadIdx.x;
  int v = (t < nb) ? part[t] : 0;
  sh[t] = v;
  __syncthreads();
  for (int d = 1; d < 256; d <<= 1) {
    int u = (t >= d) ? sh[t - d] : 0;
    __syncthreads();
    sh[t] += u;
    __syncthreads();
  }
  if (t < nb) part[t] = sh[t] - v;          // exclusive base per block
  if (t == nb - 1) offs[n] = sh[t];         // grand total
}

// ---------- stage 3: per-block exclusive scan + base; fuses dinv ----------
__global__ __launch_bounds__(256) void scan_final(
    const int* __restrict__ cnt, const int* __restrict__ part,
    int* __restrict__ offs, int* __restrict__ cur, float* __restrict__ dinv, int n) {
  __shared__ int sh[256];
  int t = threadIdx.x;
  int i = blockIdx.x * 256 + t;
  int v = (i < n) ? cnt[i] : 0;
  sh[t] = v;
  __syncthreads();
  for (int d = 1; d < 256; d <<= 1) {
    int u = (t >= d) ? sh[t - d] : 0;
    __syncthreads();
    sh[t] += u;
    __syncthreads();
  }
  if (i < n) {
    int excl = part[blockIdx.x] + sh[t] - v;
    offs[i] = excl;
    cur[i] = excl;
    int c = v < 1 ? 1 : v;
    dinv[i] = 1.0f / sqrtf((float)c);
  }
}

__global__ void scatter_edges(const int* __restrict__ src, const int* __restrict__ dst,
                              int* __restrict__ cur, int* __restrict__ csr, int e, int n) {
  int i = blockIdx.x * blockDim.x + threadIdx.x;
  if (i < e + n) {
    int s, d;
    if (i < e) { s = src[i]; d = dst[i]; } else { s = i - e; d = i - e; }
    int pos = atomicAdd(&cur[d], 1);
    csr[pos] = s;
  }
}

// ---------- bf16 MFMA GEMM: C[M][Nc] = A[M][K] * Bt[Nc][K]^T ----------
// BK=64: 2-barrier K-step with 32 MFMA + 16 ds_read_b128 per iteration.
// Staging: 2 threads/row, each stages 32 contiguous k-elems (f32 converts in-reg).
template <bool AF32, bool OUTBF>
__global__ __launch_bounds__(256) void gemm_bt(
    const void* __restrict__ Av, const __hip_bfloat16* __restrict__ Bt,
    void* __restrict__ Cv, int M, int Nc, int K) {
  __shared__ __hip_bfloat16 Ash[128][72];
  __shared__ __hip_bfloat16 Bsh[128][72];
  const int tid = threadIdx.x;
  const int lane = tid & 63;
  const int w = tid >> 6;
  const int wr = (w >> 1) * 64, wc = (w & 1) * 64;
  const int row0 = blockIdx.x * 128, col0 = blockIdx.y * 128;
  const int sr = tid >> 1;          // 0..127
  const int sc = (tid & 1) * 32;    // 0 or 32
  const int lrow = lane & 15;
  const int lk = (lane >> 4) * 8;

  f32x4 zero4 = {0.f, 0.f, 0.f, 0.f};
  f32x4 acc[4][4];
#pragma unroll
  for (int i = 0; i < 4; i++)
#pragma unroll
    for (int j = 0; j < 4; j++) acc[i][j] = zero4;

  u16x8 z8 = {0, 0, 0, 0, 0, 0, 0, 0};
  u16x8 za[4], zb[4];

  auto loadA = [&](int kt) {
    int rr = row0 + sr;
    if (rr >= M) {
#pragma unroll
      for (int q = 0; q < 4; ++q) za[q] = z8;
      return;
    }
    if constexpr (AF32) {
      const float* ap = (const float*)Av + (size_t)rr * K + kt + sc;
#pragma unroll
      for (int q = 0; q < 4; ++q) {
        float4 f0 = *(const float4*)(ap + q * 8);
        float4 f1 = *(const float4*)(ap + q * 8 + 4);
        u16x8 o;
        o[0] = f2bf(f0.x); o[1] = f2bf(f0.y); o[2] = f2bf(f0.z); o[3] = f2bf(f0.w);
        o[4] = f2bf(f1.x); o[5] = f2bf(f1.y); o[6] = f2bf(f1.z); o[7] = f2bf(f1.w);
        za[q] = o;
      }
    } else {
      const __hip_bfloat16* ap = (const __hip_bfloat16*)Av + (size_t)rr * K + kt + sc;
#pragma unroll
      for (int q = 0; q < 4; ++q) za[q] = *(const u16x8*)(ap + q * 8);
    }
  };
  auto loadB = [&](int kt) {
    int rr = col0 + sr;
    if (rr >= Nc) {
#pragma unroll
      for (int q = 0; q < 4; ++q) zb[q] = z8;
      return;
    }
    const __hip_bfloat16* bp = Bt + (size_t)rr * K + kt + sc;
#pragma unroll
    for (int q = 0; q < 4; ++q) zb[q] = *(const u16x8*)(bp + q * 8);
  };

  loadA(0);
  loadB(0);

  for (int kt = 0; kt < K; kt += 64) {
    __syncthreads();
#pragma unroll
    for (int q = 0; q < 4; ++q) {
      *(u16x8*)&Ash[sr][sc + q * 8] = za[q];
      *(u16x8*)&Bsh[sr][sc + q * 8] = zb[q];
    }
    __syncthreads();
    int kn = kt + 64;
    if (kn < K) { loadA(kn); loadB(kn); }
#pragma unroll
    for (int kk = 0; kk < 64; kk += 32) {
      bf16x8 av[4], bv[4];
#pragma unroll
      for (int i = 0; i < 4; i++) av[i] = *(const bf16x8*)&Ash[wr + i * 16 + lrow][kk + lk];
#pragma unroll
      for (int j = 0; j < 4; j++) bv[j] = *(const bf16x8*)&Bsh[wc + j * 16 + lrow][kk + lk];
#pragma unroll
      for (int i = 0; i < 4; i++)
#pragma unroll
        for (int j = 0; j < 4; j++)
          acc[i][j] = __builtin_amdgcn_mfma_f32_16x16x32_bf16(av[i], bv[j], acc[i][j], 0, 0, 0);
    }
  }

#pragma unroll
  for (int i = 0; i < 4; i++) {
#pragma unroll
    for (int r = 0; r < 4; r++) {
      int rr = row0 + wr + i * 16 + (lane >> 4) * 4 + r;
      if (rr < M) {
#pragma unroll
        for (int j = 0; j < 4; j++) {
          int cc = col0 + wc + j * 16 + (lane & 15);
          if (cc < Nc) {
            if constexpr (OUTBF) {
              ((__hip_bfloat16*)Cv)[(size_t)rr * Nc + cc] = __float2bfloat16(acc[i][j][r]);
            } else {
              ((float*)Cv)[(size_t)rr * Nc + cc] = acc[i][j][r];
            }
          }
        }
      }
    }
  }
}

// ---------- per-node attention logits: a_src[n][h], a_dst[n][h] (h in bf16) ----------
__global__ __launch_bounds__(256) void att_kernel(
    const __hip_bfloat16* __restrict__ h, const float* __restrict__ att_s, const float* __restrict__ att_d,
    float* __restrict__ a_src, float* __restrict__ a_dst, int n) {
  int wid = (int)(((size_t)blockIdx.x * blockDim.x + threadIdx.x) >> 6);
  if (wid >= n) return;
  int lane = threadIdx.x & 63;
  int c0 = lane * 4;
  u16x4 hv = *(const u16x4*)(h + (size_t)wid * 256 + c0);
  float h0 = bf2f(hv[0]), h1_ = bf2f(hv[1]), h2_ = bf2f(hv[2]), h3 = bf2f(hv[3]);
  float4 as = *(const float4*)(att_s + c0);
  float4 ad = *(const float4*)(att_d + c0);
  float ds_ = h0 * as.x + h1_ * as.y + h2_ * as.z + h3 * as.w;
  float dd_ = h0 * ad.x + h1_ * ad.y + h2_ * ad.z + h3 * ad.w;
#pragma unroll
  for (int m = 1; m < 16; m <<= 1) {
    ds_ += __shfl_xor(ds_, m);
    dd_ += __shfl_xor(dd_, m);
  }
  if ((lane & 15) == 0) {
    a_src[wid * 4 + (lane >> 4)] = ds_;
    a_dst[wid * 4 + (lane >> 4)] = dd_;
  }
}

// ---------- global per-head maxes of a_src / a_dst ----------
__global__ __launch_bounds__(256) void att_max(
    const float* __restrict__ asrc, const float* __restrict__ adst,
    unsigned* __restrict__ gkey, int n) {
  float ms0 = -1e30f, ms1 = -1e30f, ms2 = -1e30f, ms3 = -1e30f;
  float md0 = -1e30f, md1 = -1e30f, md2 = -1e30f, md3 = -1e30f;
  for (int i = blockIdx.x * blockDim.x + threadIdx.x; i < n; i += gridDim.x * blockDim.x) {
    float4 s = *(const float4*)(asrc + (size_t)i * 4);
    float4 d = *(const float4*)(adst + (size_t)i * 4);
    ms0 = fmaxf(ms0, s.x); ms1 = fmaxf(ms1, s.y); ms2 = fmaxf(ms2, s.z); ms3 = fmaxf(ms3, s.w);
    md0 = fmaxf(md0, d.x); md1 = fmaxf(md1, d.y); md2 = fmaxf(md2, d.z); md3 = fmaxf(md3, d.w);
  }
#pragma unroll
  for (int o = 32; o; o >>= 1) {
    ms0 = fmaxf(ms0, __shfl_xor(ms0, o)); ms1 = fmaxf(ms1, __shfl_xor(ms1, o));
    ms2 = fmaxf(ms2, __shfl_xor(ms2, o)); ms3 = fmaxf(ms3, __shfl_xor(ms3, o));
    md0 = fmaxf(md0, __shfl_xor(md0, o)); md1 = fmaxf(md1, __shfl_xor(md1, o));
    md2 = fmaxf(md2, __shfl_xor(md2, o)); md3 = fmaxf(md3, __shfl_xor(md3, o));
  }
  if ((threadIdx.x & 63) == 0) {
    atomicMax(&gkey[0], fkey(ms0)); atomicMax(&gkey[1], fkey(ms1));
    atomicMax(&gkey[2], fkey(ms2)); atomicMax(&gkey[3], fkey(ms3));
    atomicMax(&gkey[4], fkey(md0)); atomicMax(&gkey[5], fkey(md1));
    atomicMax(&gkey[6], fkey(md2)); atomicMax(&gkey[7], fkey(md3));
  }
}

// ---------- GAT aggregate: one wave per dst node, 2 edges/load (half-wave split) ----------
__global__ __launch_bounds__(256) void gat_aggregate(
    const __hip_bfloat16* __restrict__ h, const float* __restrict__ a_src, const float* __restrict__ a_dst,
    const int* __restrict__ offs, const int* __restrict__ csr, const float* __restrict__ b1,
    const unsigned* __restrict__ gkey, __hip_bfloat16* __restrict__ h1, int n) {
  int wid = (int)(((size_t)blockIdx.x * blockDim.x + threadIdx.x) >> 6);
  if (wid >= n) return;
  int lane = threadIdx.x & 63;
  int half = lane >> 5;
  int l5 = lane & 31;
  int c0 = l5 * 8;          // 8 channels per lane, 32 lanes cover 256
  int hl = l5 >> 3;         // head = c0/64
  int base = offs[wid];
  int deg = offs[wid + 1] - base;

  float mh = keyf(gkey[hl]) + keyf(gkey[4 + hl]);
  mh = mh > 0.f ? mh : 0.2f * mh;           // lrelu of upper bound >= all alpha
  float adh = a_dst[wid * 4 + hl];

  float den = 0.f;
  float acc[8] = {0.f, 0.f, 0.f, 0.f, 0.f, 0.f, 0.f, 0.f};
  int P = deg >> 1;
  int i = 0;
  for (; i + 2 <= P; i += 2) {
    int sA = csr[base + 2 * i + half];
    int sB = csr[base + 2 * i + 2 + half];
    float aA = a_src[sA * 4 + hl];
    float aB = a_src[sB * 4 + hl];
    u16x8 rA = *(const u16x8*)(h + (size_t)sA * 256 + c0);
    u16x8 rB = *(const u16x8*)(h + (size_t)sB * 256 + c0);
    float vA = aA + adh; vA = vA > 0.f ? vA : 0.2f * vA;
    float vB = aB + adh; vB = vB > 0.f ? vB : 0.2f * vB;
    float eA = __expf(vA - mh);
    float eB = __expf(vB - mh);
    den += eA + eB;
#pragma unroll
    for (int ch = 0; ch < 8; ++ch) acc[ch] += eA * bf2f(rA[ch]) + eB * bf2f(rB[ch]);
  }
  if (i < P) {
    int sA = csr[base + 2 * i + half];
    float aA = a_src[sA * 4 + hl];
    u16x8 rA = *(const u16x8*)(h + (size_t)sA * 256 + c0);
    float vA = aA + adh; vA = vA > 0.f ? vA : 0.2f * vA;
    float eA = __expf(vA - mh);
    den += eA;
#pragma unroll
    for (int ch = 0; ch < 8; ++ch) acc[ch] += eA * bf2f(rA[ch]);
  }
  if ((deg & 1) && half == 0) {
    int sA = csr[base + deg - 1];
    float aA = a_src[sA * 4 + hl];
    u16x8 rA = *(const u16x8*)(h + (size_t)sA * 256 + c0);
    float vA = aA + adh; vA = vA > 0.f ? vA : 0.2f * vA;
    float eA = __expf(vA - mh);
    den += eA;
#pragma unroll
    for (int ch = 0; ch < 8; ++ch) acc[ch] += eA * bf2f(rA[ch]);
  }
  den += __shfl_xor(den, 32);
#pragma unroll
  for (int ch = 0; ch < 8; ++ch) acc[ch] += __shfl_xor(acc[ch], 32);

  if (half == 0) {
    float inv = 1.f / (den + 1e-16f);
    float4 bb0 = *(const float4*)(b1 + c0);
    float4 bb1 = *(const float4*)(b1 + c0 + 4);
    u16x8 o;
    o[0] = f2bf(fmaxf(acc[0] * inv + bb0.x, 0.f));
    o[1] = f2bf(fmaxf(acc[1] * inv + bb0.y, 0.f));
    o[2] = f2bf(fmaxf(acc[2] * inv + bb0.z, 0.f));
    o[3] = f2bf(fmaxf(acc[3] * inv + bb0.w, 0.f));
    o[4] = f2bf(fmaxf(acc[4] * inv + bb1.x, 0.f));
    o[5] = f2bf(fmaxf(acc[5] * inv + bb1.y, 0.f));
    o[6] = f2bf(fmaxf(acc[6] * inv + bb1.z, 0.f));
    o[7] = f2bf(fmaxf(acc[7] * inv + bb1.w, 0.f));
    *(u16x8*)(h1 + (size_t)wid * 256 + c0) = o;
  }
}

// ---------- GCN aggregate: one wave per dst node, 2 edges/load (half-wave split) ----------
__global__ __launch_bounds__(256) void gcn_aggregate(
    const __hip_bfloat16* __restrict__ h2, const int* __restrict__ offs, const int* __restrict__ csr,
    const float* __restrict__ dinv, const float* __restrict__ b2,
    __hip_bfloat16* __restrict__ out2, int n) {
  int wid = (int)(((size_t)blockIdx.x * blockDim.x + threadIdx.x) >> 6);
  if (wid >= n) return;
  int lane = threadIdx.x & 63;
  int half = lane >> 5;
  int l5 = lane & 31;
  int c0 = l5 * 8;
  int base = offs[wid];
  int deg = offs[wid + 1] - base;
  float dn = dinv[wid];
  float acc[8] = {0.f, 0.f, 0.f, 0.f, 0.f, 0.f, 0.f, 0.f};
  int P = deg >> 1;
  int i = 0;
  for (; i + 2 <= P; i += 2) {
    int sA = csr[base + 2 * i + half];
    int sB = csr[base + 2 * i + 2 + half];
    float wA = dinv[sA], wB = dinv[sB];
    u16x8 rA = *(const u16x8*)(h2 + (size_t)sA * 256 + c0);
    u16x8 rB = *(const u16x8*)(h2 + (size_t)sB * 256 + c0);
#pragma unroll
    for (int ch = 0; ch < 8; ++ch) acc[ch] += wA * bf2f(rA[ch]) + wB * bf2f(rB[ch]);
  }
  if (i < P) {
    int sA = csr[base + 2 * i + half];
    float wA = dinv[sA];
    u16x8 rA = *(const u16x8*)(h2 + (size_t)sA * 256 + c0);
#pragma unroll
    for (int ch = 0; ch < 8; ++ch) acc[ch] += wA * bf2f(rA[ch]);
  }
  if ((deg & 1) && half == 0) {
    int sA = csr[base + deg - 1];
    float wA = dinv[sA];
    u16x8 rA = *(const u16x8*)(h2 + (size_t)sA * 256 + c0);
#pragma unroll
    for (int ch = 0; ch < 8; ++ch) acc[ch] += wA * bf2f(rA[ch]);
  }
#pragma unroll
  for (int ch = 0; ch < 8; ++ch) acc[ch] += __shfl_xor(acc[ch], 32);

  if (half == 0) {
    float4 bb0 = *(const float4*)(b2 + c0);
    float4 bb1 = *(const float4*)(b2 + c0 + 4);
    u16x8 o;
    o[0] = f2bf(acc[0] * dn + bb0.x);
    o[1] = f2bf(acc[1] * dn + bb0.y);
    o[2] = f2bf(acc[2] * dn + bb0.z);
    o[3] = f2bf(acc[3] * dn + bb0.w);
    o[4] = f2bf(acc[4] * dn + bb1.x);
    o[5] = f2bf(acc[5] * dn + bb1.y);
    o[6] = f2bf(acc[6] * dn + bb1.z);
    o[7] = f2bf(acc[7] * dn + bb1.w);
    *(u16x8*)(out2 + (size_t)wid * 256 + c0) = o;
  }
}

// ---------- mean pool, stage 1: 64 rows/block, 4 waves x 16 rows, LDS-combine ----------
__global__ __launch_bounds__(256) void pool_partial(
    const __hip_bfloat16* __restrict__ out2, const int* __restrict__ batch,
    float* __restrict__ accum, int n) {
  __shared__ float lds[3][256];
  int tid = threadIdx.x;
  int w = tid >> 6, lane = tid & 63;
  int base = blockIdx.x * 64;
  if (base >= n) return;
  int last = base + 63; if (last > n - 1) last = n - 1;
  int g0 = batch[base], g1 = batch[last];
  int c0 = lane * 4;
  const unsigned short* o16 = (const unsigned short*)out2;
  int rs = base + w * 16;
  int re = rs + 16; if (re > n) re = n;
  float a0 = 0.f, a1 = 0.f, a2 = 0.f, a3 = 0.f;

  if (g0 == g1) {
    // fast path: whole block is one group; no per-row batch reads
    for (int r = rs; r < re; ++r) {
      u16x4 v = *(const u16x4*)(o16 + (size_t)r * 256 + c0);
      a0 += bf2f(v[0]); a1 += bf2f(v[1]); a2 += bf2f(v[2]); a3 += bf2f(v[3]);
    }
    if (w > 0) {
      lds[w - 1][c0] = a0; lds[w - 1][c0 + 1] = a1;
      lds[w - 1][c0 + 2] = a2; lds[w - 1][c0 + 3] = a3;
    }
    __syncthreads();
    if (w == 0) {
#pragma unroll
      for (int k = 0; k < 3; ++k) {
        a0 += lds[k][c0]; a1 += lds[k][c0 + 1];
        a2 += lds[k][c0 + 2]; a3 += lds[k][c0 + 3];
      }
      float* dst = &accum[(size_t)g0 * 256 + c0];
      atomicAdd(dst, a0); atomicAdd(dst + 1, a1);
      atomicAdd(dst + 2, a2); atomicAdd(dst + 3, a3);
    }
  } else {
    // slow path: group boundary inside block — per-wave exact flushes
    int curg = -1;
    for (int r = rs; r < re; ++r) {
      int g = batch[r];
      if (g != curg) {
        if (curg >= 0) {
          float* dst = &accum[(size_t)curg * 256 + c0];
          atomicAdd(dst, a0); atomicAdd(dst + 1, a1);
          atomicAdd(dst + 2, a2); atomicAdd(dst + 3, a3);
          a0 = a1 = a2 = a3 = 0.f;
        }
        curg = g;
      }
      u16x4 v = *(const u16x4*)(o16 + (size_t)r * 256 + c0);
      a0 += bf2f(v[0]); a1 += bf2f(v[1]); a2 += bf2f(v[2]); a3 += bf2f(v[3]);
    }
    if (curg >= 0) {
      float* dst = &accum[(size_t)curg * 256 + c0];
      atomicAdd(dst, a0); atomicAdd(dst + 1, a1);
      atomicAdd(dst + 2, a2); atomicAdd(dst + 3, a3);
    }
  }
}

// ---------- mean pool, stage 2: divide by group count ----------
__global__ __launch_bounds__(256) void pool_finalize(
    const float* __restrict__ accum, const int* __restrict__ batch,
    float* __restrict__ out, int n) {
  __shared__ int sb[2];
  int g = blockIdx.x;
  int t = threadIdx.x;
  if (t < 2) {
    int target = g + t;
    int lo = 0, hi = n;
    while (lo < hi) {
      int mid = (lo + hi) >> 1;
      if (batch[mid] < target) lo = mid + 1; else hi = mid;
    }
    sb[t] = lo;
  }
  __syncthreads();
  int cnt = sb[1] - sb[0];
  out[g * 256 + t] = accum[g * 256 + t] / fmaxf((float)cnt, 1.0f);
}

extern "C" void kernel_launch(void* const* d_in, const int* in_sizes, int n_in,
                              void* d_out, int out_size, void* d_ws, size_t ws_size,
                              hipStream_t stream) {
  const float* x = (const float*)d_in[0];
  const int* ei = (const int*)d_in[1];
  const int* batch = (const int*)d_in[2];
  const float* W1 = (const float*)d_in[3];
  const float* att_s = (const float*)d_in[4];
  const float* att_d = (const float*)d_in[5];
  const float* b1 = (const float*)d_in[6];
  const float* W2 = (const float*)d_in[7];
  const float* b2 = (const float*)d_in[8];
  float* out = (float*)d_out;

  const int n = N_NODES;
  const int e = in_sizes[1] / 2;
  const int* esrc = ei;
  const int* edst = ei + e;
  const int nb = (n + 255) / 256;   // 196 scan blocks

  char* p = (char*)d_ws;
  size_t off_ = 0;
  auto alloc = [&](size_t b) -> void* {
    void* r = p + off_;
    off_ = (off_ + b + 255) & ~(size_t)255;
    return r;
  };
  __hip_bfloat16* hb = (__hip_bfloat16*)alloc((size_t)n * 256 * 2);   // 25.6 MB
  __hip_bfloat16* h1b = (__hip_bfloat16*)alloc((size_t)n * 256 * 2);  // 25.6 MB
  __hip_bfloat16* h2b = (__hip_bfloat16*)alloc((size_t)n * 256 * 2);  // 25.6 MB
  __hip_bfloat16* out2 = (__hip_bfloat16*)alloc((size_t)n * 256 * 2); // 25.6 MB
  float* asrc = (float*)alloc((size_t)n * 4 * 4);
  float* adst = (float*)alloc((size_t)n * 4 * 4);
  int* cnt = (int*)alloc((size_t)n * 4);
  int* offs = (int*)alloc((size_t)(n + 1) * 4);
  int* cur = (int*)alloc((size_t)n * 4);
  int* csr = (int*)alloc((size_t)(e + n) * 4);
  float* dinv = (float*)alloc((size_t)n * 4);
  int* part = (int*)alloc((size_t)nb * 4);
  __hip_bfloat16* W1t = (__hip_bfloat16*)alloc(512 * 256 * 2);
  __hip_bfloat16* W2t = (__hip_bfloat16*)alloc(256 * 256 * 2);
  float* accum = (float*)alloc((size_t)N_GROUPS * 256 * 4);
  unsigned* gkey = (unsigned*)alloc(8 * 4);

  // weight transposes + zeroing
  cvt_transpose<<<(512 * 256 + 255) / 256, 256, 0, stream>>>(W1, W1t, 512, 256);
  cvt_transpose<<<(256 * 256 + 255) / 256, 256, 0, stream>>>(W2, W2t, 256, 256);
  hipMemsetAsync(cnt, 0, (size_t)n * 4, stream);
  hipMemsetAsync(accum, 0, (size_t)N_GROUPS * 256 * 4, stream);
  hipMemsetAsync(gkey, 0, 8 * 4, stream);

  // GEMM1: h = x @ W1   [n,512]x[512,256] -> bf16 (f32 A staged+converted in-kernel)
  dim3 g1((n + 127) / 128, 2);
  gemm_bt<true, true><<<g1, 256, 0, stream>>>(x, W1t, hb, n, 256, 512);

  // attention logits
  att_kernel<<<(n + 3) / 4, 256, 0, stream>>>(hb, att_s, att_d, asrc, adst, n);

  // CSR by dst (with self loops) — hierarchical scan, dinv fused in stage 3
  count_deg<<<(e + n + 255) / 256, 256, 0, stream>>>(edst, cnt, e, n);
  scan_part<<<nb, 256, 0, stream>>>(cnt, part, n);
  scan_mid<<<1, 256, 0, stream>>>(part, offs, nb, n);
  scan_final<<<nb, 256, 0, stream>>>(cnt, part, offs, cur, dinv, n);
  scatter_edges<<<(e + n + 255) / 256, 256, 0, stream>>>(esrc, edst, cur, csr, e, n);

  // per-head global alpha upper bound
  att_max<<<128, 256, 0, stream>>>(asrc, adst, gkey, n);

  // GAT aggregate + bias + relu -> bf16 h1
  gat_aggregate<<<(n + 3) / 4, 256, 0, stream>>>(hb, asrc, adst, offs, csr, b1, gkey, h1b, n);

  // GEMM2: h2 = h1 @ W2  [n,256]x[256,256] -> bf16
  gemm_bt<false, true><<<g1, 256, 0, stream>>>(h1b, W2t, h2b, n, 256, 256);

  // GCN aggregate -> bf16 out2
  gcn_aggregate<<<(n + 3) / 4, 256, 0, stream>>>(h2b, offs, csr, dinv, b2, out2, n);

  // mean pool (two-stage)
  pool_partial<<<(n + 63) / 64, 256, 0, stream>>>(out2, batch, accum, n);
  pool_finalize<<<N_GROUPS, 256, 0, stream>>>(accum, batch, out, n);
}